// Round 5
// baseline (1056.454 us; speedup 1.0000x reference)
//
#include <hip/hip_runtime.h>
#include <cstddef>
#include <cstring>

#define B_    2
#define L_    2048
#define DM_   1024
#define NH_   16
#define DH_   64
#define SCALE_ 0.125f   // 1/sqrt(64)

typedef __bf16 bf16x8 __attribute__((ext_vector_type(8)));
typedef float  f32x4  __attribute__((ext_vector_type(4)));
typedef unsigned short ushort8v __attribute__((ext_vector_type(8)));
typedef unsigned long long u64;
typedef unsigned int u32;

__device__ __forceinline__ u32 flipf(float f) {
    u32 u = __float_as_uint(f);
    return (u & 0x80000000u) ? ~u : (u | 0x80000000u);
}
__device__ __forceinline__ float unflipf(u32 k) {
    u32 u = (k & 0x80000000u) ? (k ^ 0x80000000u) : ~k;
    return __uint_as_float(u);
}
__device__ __forceinline__ float bf2f(unsigned short u) {
    return __uint_as_float(((u32)u) << 16);
}
__device__ __forceinline__ unsigned short f2bf(float f) {
    __bf16 h = (__bf16)f;
    unsigned short u;
    __builtin_memcpy(&u, &h, 2);
    return u;
}

// ---------------------------------------------------------------------------
// GEMM 128x128 tile, 8x8 microtile, fp32, C = A(MxK) @ W(KxN)
// ---------------------------------------------------------------------------
__global__ __launch_bounds__(256)
void gemm128(const float* __restrict__ A, const float* __restrict__ W,
             float* __restrict__ C, int N, int K) {
    __shared__ float As[16][136];
    __shared__ float Ws[16][136];
    const int t  = threadIdx.x;
    const int bm = blockIdx.y << 7;
    const int bn = blockIdx.x << 7;
    const int tm = (t >> 4) << 3;
    const int tn = (t & 15) << 3;
    float acc[8][8] = {};
    const int am = t >> 1;
    const int ak = (t & 1) << 3;
    const int wk = t >> 4;
    const int wn = (t & 15) << 3;
    const float* Ap = A + (size_t)(bm + am) * K + ak;
    const float* Wp = W + (size_t)wk * N + bn + wn;
    for (int k0 = 0; k0 < K; k0 += 16) {
        float4 a0 = *(const float4*)(Ap + k0);
        float4 a1 = *(const float4*)(Ap + k0 + 4);
        float4 w0 = *(const float4*)(Wp + (size_t)k0 * N);
        float4 w1 = *(const float4*)(Wp + (size_t)k0 * N + 4);
        __syncthreads();
        As[ak+0][am] = a0.x; As[ak+1][am] = a0.y; As[ak+2][am] = a0.z; As[ak+3][am] = a0.w;
        As[ak+4][am] = a1.x; As[ak+5][am] = a1.y; As[ak+6][am] = a1.z; As[ak+7][am] = a1.w;
        *(float4*)&Ws[wk][wn]     = w0;
        *(float4*)&Ws[wk][wn + 4] = w1;
        __syncthreads();
        #pragma unroll
        for (int kk = 0; kk < 16; ++kk) {
            float a_[8], w_[8];
            *(float4*)&a_[0] = *(const float4*)&As[kk][tm];
            *(float4*)&a_[4] = *(const float4*)&As[kk][tm + 4];
            *(float4*)&w_[0] = *(const float4*)&Ws[kk][tn];
            *(float4*)&w_[4] = *(const float4*)&Ws[kk][tn + 4];
            #pragma unroll
            for (int i = 0; i < 8; ++i)
                #pragma unroll
                for (int j = 0; j < 8; ++j)
                    acc[i][j] += a_[i] * w_[j];
        }
    }
    #pragma unroll
    for (int i = 0; i < 8; ++i) {
        float* Cp = C + (size_t)(bm + tm + i) * N + bn + tn;
        float4 o0 = {acc[i][0], acc[i][1], acc[i][2], acc[i][3]};
        float4 o1 = {acc[i][4], acc[i][5], acc[i][6], acc[i][7]};
        *(float4*)Cp       = o0;
        *(float4*)(Cp + 4) = o1;
    }
}

// ---------------------------------------------------------------------------
// GEMM 64x64 tile, 4x4 microtile (skinny kv projection, N=128)
// ---------------------------------------------------------------------------
__global__ __launch_bounds__(256)
void gemm64(const float* __restrict__ A, const float* __restrict__ W,
            float* __restrict__ C, int N, int K) {
    __shared__ float As[16][68];
    __shared__ float Ws[16][68];
    const int t  = threadIdx.x;
    const int bm = blockIdx.y << 6;
    const int bn = blockIdx.x << 6;
    const int tm = (t >> 4) << 2;
    const int tn = (t & 15) << 2;
    float acc[4][4] = {};
    const int am = t >> 2;
    const int ak = (t & 3) << 2;
    const int wk = t >> 4;
    const int wn = (t & 15) << 2;
    const float* Ap = A + (size_t)(bm + am) * K + ak;
    const float* Wp = W + (size_t)wk * N + bn + wn;
    for (int k0 = 0; k0 < K; k0 += 16) {
        float4 av = *(const float4*)(Ap + k0);
        float4 wv = *(const float4*)(Wp + (size_t)k0 * N);
        __syncthreads();
        As[ak+0][am] = av.x; As[ak+1][am] = av.y; As[ak+2][am] = av.z; As[ak+3][am] = av.w;
        *(float4*)&Ws[wk][wn] = wv;
        __syncthreads();
        #pragma unroll
        for (int kk = 0; kk < 16; ++kk) {
            float a_[4], w_[4];
            *(float4*)&a_[0] = *(const float4*)&As[kk][tm];
            *(float4*)&w_[0] = *(const float4*)&Ws[kk][tn];
            #pragma unroll
            for (int i = 0; i < 4; ++i)
                #pragma unroll
                for (int j = 0; j < 4; ++j)
                    acc[i][j] += a_[i] * w_[j];
        }
    }
    #pragma unroll
    for (int i = 0; i < 4; ++i) {
        float4 o = {acc[i][0], acc[i][1], acc[i][2], acc[i][3]};
        *(float4*)(C + (size_t)(bm + tm + i) * N + bn + tn) = o;
    }
}

// ---------------------------------------------------------------------------
// Column (sequence-axis) L2 norms of kv -> inv_norm[b][c]
// ---------------------------------------------------------------------------
__global__ __launch_bounds__(256)
void col_norms(const float* __restrict__ kv, float* __restrict__ invn) {
    const int bc = blockIdx.x;
    const int b  = bc >> 7;
    const int c  = bc & 127;
    const int t  = threadIdx.x;
    const float* base = kv + (size_t)b * L_ * 128 + c;
    float ss = 0.f;
    for (int l = t; l < L_; l += 256) {
        float x = base[(size_t)l * 128];
        ss += x * x;
    }
    #pragma unroll
    for (int off = 32; off; off >>= 1) ss += __shfl_xor(ss, off);
    __shared__ float red[4];
    if ((t & 63) == 0) red[t >> 6] = ss;
    __syncthreads();
    if (t == 0) {
        float tot = red[0] + red[1] + red[2] + red[3];
        invn[bc] = 1.f / fmaxf(sqrtf(tot), 1e-12f);
    }
}

// ---------------------------------------------------------------------------
// Scale kv by inv-norms: kn fp32 (b,l,64), kh bf16 (b,l,64), vT bf16 (b,64,l)
// ---------------------------------------------------------------------------
__global__ __launch_bounds__(256)
void scale_kv(const float* __restrict__ kv, const float* __restrict__ invn,
              float* __restrict__ kn, __bf16* __restrict__ kh,
              __bf16* __restrict__ vT) {
    const int b  = blockIdx.y;
    const int l0 = blockIdx.x << 6;
    const int t  = threadIdx.x;
    __shared__ float s_inv[128];
    __shared__ float s_vt[64][65];
    if (t < 128) s_inv[t] = invn[b * 128 + t];
    __syncthreads();
    #pragma unroll
    for (int rep = 0; rep < 8; ++rep) {
        int idx = (rep << 8) + t;          // 0..2047
        int li  = idx >> 5;                // 0..63
        int c4  = (idx & 31) << 2;         // 0..124
        float4 x = *(const float4*)(kv + ((size_t)(b * L_ + l0 + li)) * 128 + c4);
        x.x *= s_inv[c4]; x.y *= s_inv[c4+1]; x.z *= s_inv[c4+2]; x.w *= s_inv[c4+3];
        if (c4 < 64) {
            size_t o = ((size_t)(b * L_ + l0 + li)) * DH_ + c4;
            *(float4*)(kn + o) = x;
            kh[o+0] = (__bf16)x.x; kh[o+1] = (__bf16)x.y;
            kh[o+2] = (__bf16)x.z; kh[o+3] = (__bf16)x.w;
        } else {
            int d = c4 - 64;
            s_vt[d+0][li] = x.x; s_vt[d+1][li] = x.y; s_vt[d+2][li] = x.z; s_vt[d+3][li] = x.w;
        }
    }
    __syncthreads();
    #pragma unroll
    for (int rep = 0; rep < 4; ++rep) {
        int idx = (rep << 8) + t;          // 0..1023
        int d   = idx >> 4;                // 0..63
        int j   = (idx & 15) << 2;         // 0..60
        size_t o = ((size_t)b * DH_ + d) * L_ + l0 + j;
        vT[o+0] = (__bf16)s_vt[d][j+0];
        vT[o+1] = (__bf16)s_vt[d][j+1];
        vT[o+2] = (__bf16)s_vt[d][j+2];
        vT[o+3] = (__bf16)s_vt[d][j+3];
    }
}

// ---------------------------------------------------------------------------
// Fused attention + exact top-32.  Block: 1024 thr (16 waves) = (b,h,16 rows).
// R5 change: __launch_bounds__(1024,4) -> 128-VGPR budget so the compiler can
// keep the gather/stream loads in flight (r4's (1024,8) pinned VGPR=32 and
// serialized every L2 round trip).  Load-heavy phases restructured to batch.
// ---------------------------------------------------------------------------
#define SSTRIDE_ 2072   // ushort row stride

__global__ __launch_bounds__(1024, 4)
void attn_topk(const float* __restrict__ q,    // (B, L, 1024) fp32
               const float* __restrict__ kn,   // (B, L, 64)  fp32
               const __bf16* __restrict__ kh,  // (B, L, 64)  bf16
               const __bf16* __restrict__ vT,  // (B, 64, L)  bf16
               float* __restrict__ attn) {     // (B, L, 1024)
    const int l0   = blockIdx.x << 4;
    const int h    = blockIdx.y;
    const int b    = blockIdx.z;
    const int t    = threadIdx.x;
    const int w    = t >> 6;          // wave 0..15
    const int lane = t & 63;
    const int quad = lane >> 4;
    const int n15  = lane & 15;

    __shared__ unsigned short s_sims[16 * SSTRIDE_];        // 66,304 B
    __shared__ unsigned short s_cand[16][128];              //  4,096 B
    __shared__ __align__(16) u64 s_sel[16][32];             //  8,192 B
    __shared__ float s_denom[16];
    __shared__ float s_local[16][66];                       //  4,224 B

    // ---- init accumulators ----
    {
        float* sl = &s_local[0][0];
        for (int i = t; i < 16 * 66; i += 1024) sl[i] = 0.f;
        if (t < 16) s_denom[t] = 0.f;
    }

    // ---- phase S: sims via bf16 MFMA (wave w -> m in [128w,128w+128)) ----
    {
        bf16x8 qf[2];
        const float* qp = q + ((size_t)(b * L_ + l0 + n15)) * DM_ + h * DH_ + (quad << 3);
        #pragma unroll
        for (int ks = 0; ks < 2; ++ks) {
            float4 x0 = *(const float4*)(qp + (ks << 5));
            float4 x1 = *(const float4*)(qp + (ks << 5) + 4);
            float xv[8] = {x0.x, x0.y, x0.z, x0.w, x1.x, x1.y, x1.z, x1.w};
            #pragma unroll
            for (int i2 = 0; i2 < 8; ++i2) qf[ks][i2] = (__bf16)xv[i2];
        }
        const __bf16* khb = kh + (size_t)b * L_ * DH_ + (size_t)((w << 7) + n15) * DH_ + (quad << 3);
        // batch all 16 fragment loads (128 B/lane in flight), then MFMA+store
        bf16x8 kf[16];
        #pragma unroll
        for (int j = 0; j < 8; ++j) {
            kf[2*j]   = *(const bf16x8*)(khb + (size_t)(j << 4) * DH_);
            kf[2*j+1] = *(const bf16x8*)(khb + (size_t)(j << 4) * DH_ + 32);
        }
        #pragma unroll
        for (int j = 0; j < 8; ++j) {
            int m0 = (w << 7) + (j << 4);
            f32x4 acc = {0.f, 0.f, 0.f, 0.f};
            acc = __builtin_amdgcn_mfma_f32_16x16x32_bf16(qf[0], kf[2*j],   acc, 0, 0, 0);
            acc = __builtin_amdgcn_mfma_f32_16x16x32_bf16(qf[1], kf[2*j+1], acc, 0, 0, 0);
            #pragma unroll
            for (int rr = 0; rr < 4; ++rr)
                s_sims[((quad << 2) + rr) * SSTRIDE_ + m0 + n15] = f2bf(acc[rr]);
        }
    }
    __syncthreads();   // #1: sims + zeros visible

    // ---- phase T: threshold scan + candidate compaction (wave w = row w) ----
    int C;
    {
        const int r = w;
        const unsigned short* srow = s_sims + r * SSTRIDE_;
        ushort8v rv[4];
        #pragma unroll
        for (int j = 0; j < 4; ++j)
            rv[j] = *(const ushort8v*)(srow + (j << 9) + (lane << 3));
        float bv = -3e38f;
        #pragma unroll
        for (int j = 0; j < 4; ++j)
            #pragma unroll
            for (int e = 0; e < 8; ++e) bv = fmaxf(bv, bf2f(rv[j][e]));
        // radix-select: 32nd-largest lane-max via ballot
        u32 key = flipf(bv);
        u32 thr = 0;
        #pragma unroll
        for (int bp = 31; bp >= 0; --bp) {
            u32 tt = thr | (1u << bp);
            if (__popcll(__ballot(key >= tt)) >= 32) thr = tt;
        }
        float thrv = unflipf(thr) - 0.01f;   // margin covers bf16 sims error
        int base = 0;
        #pragma unroll
        for (int j = 0; j < 4; ++j) {
            #pragma unroll
            for (int e = 0; e < 8; ++e) {
                bool pred = bf2f(rv[j][e]) >= thrv;
                u64 mk = __ballot(pred);
                if (pred) {
                    int pos = base + __popcll(mk & ((1ull << lane) - 1));
                    if (pos < 128)
                        s_cand[r][pos] = (unsigned short)((j << 9) + (lane << 3) + e);
                }
                base += __popcll(mk);
            }
        }
        C = base < 128 ? base : 128;
    }

    // ---- phase L1: local = exp(s*scale) @ v, bf16 MFMA, no max-subtract ----
    {
        f32x4 accL[4] = {{0,0,0,0},{0,0,0,0},{0,0,0,0},{0,0,0,0}};
        float psum = 0.f;
        const __bf16* vtb = vT + (size_t)b * DH_ * L_;
        // batch the 16 vT stream loads up front (256 B/lane in flight)
        bf16x8 bvv[4][4];
        #pragma unroll
        for (int ks = 0; ks < 4; ++ks) {
            int mb = (w << 7) + (ks << 5);
            #pragma unroll
            for (int nn = 0; nn < 4; ++nn)
                bvv[ks][nn] = *(const bf16x8*)(vtb + (size_t)((nn << 4) + n15) * L_ + mb + (quad << 3));
        }
        #pragma unroll
        for (int ks = 0; ks < 4; ++ks) {
            int mb = (w << 7) + (ks << 5);
            ushort8v pu = *(const ushort8v*)(s_sims + n15 * SSTRIDE_ + mb + (quad << 3));
            bf16x8 af;
            #pragma unroll
            for (int e = 0; e < 8; ++e) {
                float p = __expf(SCALE_ * bf2f(pu[e]));
                psum += p;
                af[e] = (__bf16)p;
            }
            #pragma unroll
            for (int nn = 0; nn < 4; ++nn)
                accL[nn] = __builtin_amdgcn_mfma_f32_16x16x32_bf16(af, bvv[ks][nn], accL[nn], 0, 0, 0);
        }
        psum += __shfl_xor(psum, 16);
        psum += __shfl_xor(psum, 32);
        if (lane < 16) atomicAdd(&s_denom[lane], psum);
        #pragma unroll
        for (int nn = 0; nn < 4; ++nn)
            #pragma unroll
            for (int rr = 0; rr < 4; ++rr)
                atomicAdd(&s_local[(quad << 2) + rr][(nn << 4) + n15], accL[nn][rr]);
    }

    // ---- phase F: exact fp32 refine + ballot radix top-32 (wave w = row w) ----
    {
        const int r = w;
        const float* knb = kn + (size_t)b * L_ * DH_;
        const float* qr  = q + ((size_t)(b * L_ + l0 + r)) * DM_ + h * DH_;
        int mA = (lane < C) ? (int)s_cand[r][lane] : 0;
        float dotA;
        {
            const float* kr = knb + (size_t)mA * DH_;
            float4 kx[16];
            #pragma unroll
            for (int d4 = 0; d4 < 16; ++d4) kx[d4] = *(const float4*)(kr + (d4 << 2));
            float dot = 0.f;
            #pragma unroll
            for (int d4 = 0; d4 < 16; ++d4) {
                float4 qx = *(const float4*)(qr + (d4 << 2));
                dot += kx[d4].x * qx.x + kx[d4].y * qx.y + kx[d4].z * qx.z + kx[d4].w * qx.w;
            }
            dotA = dot;
        }
        u32 keyA = (lane < C) ? flipf(dotA) : 0u;
        if (C <= 64) {
            u32 thr2 = 0;
            #pragma unroll
            for (int bp = 31; bp >= 0; --bp) {
                u32 tt = thr2 | (1u << bp);
                if (__popcll(__ballot(keyA >= tt)) >= 32) thr2 = tt;
            }
            bool pred = keyA >= thr2;
            u64 mk = __ballot(pred);
            float pt = __expf(SCALE_ * dotA);
            if (pred) {
                int pos = __popcll(mk & ((1ull << lane) - 1));
                if (pos < 32)
                    s_sel[r][pos] = ((u64)__float_as_uint(pt) << 32) | (u32)mA;
            }
        } else {
            int mB = (64 + lane < C) ? (int)s_cand[r][64 + lane] : 0;
            float dotB;
            {
                const float* kr = knb + (size_t)mB * DH_;
                float4 kx[16];
                #pragma unroll
                for (int d4 = 0; d4 < 16; ++d4) kx[d4] = *(const float4*)(kr + (d4 << 2));
                float dot = 0.f;
                #pragma unroll
                for (int d4 = 0; d4 < 16; ++d4) {
                    float4 qx = *(const float4*)(qr + (d4 << 2));
                    dot += kx[d4].x * qx.x + kx[d4].y * qx.y + kx[d4].z * qx.z + kx[d4].w * qx.w;
                }
                dotB = dot;
            }
            u32 keyB = (64 + lane < C) ? flipf(dotB) : 0u;
            u32 thr2 = 0;
            #pragma unroll
            for (int bp = 31; bp >= 0; --bp) {
                u32 tt = thr2 | (1u << bp);
                int c2 = __popcll(__ballot(keyA >= tt)) + __popcll(__ballot(keyB >= tt));
                if (c2 >= 32) thr2 = tt;
            }
            bool pA = keyA >= thr2, pB = keyB >= thr2;
            u64 mkA = __ballot(pA);
            u64 mkB = __ballot(pB);
            int cA = __popcll(mkA);
            float ptA = __expf(SCALE_ * dotA);
            float ptB = __expf(SCALE_ * dotB);
            if (pA) {
                int pos = __popcll(mkA & ((1ull << lane) - 1));
                if (pos < 32)
                    s_sel[r][pos] = ((u64)__float_as_uint(ptA) << 32) | (u32)mA;
            }
            if (pB) {
                int pos = cA + __popcll(mkB & ((1ull << lane) - 1));
                if (pos < 32)
                    s_sel[r][pos] = ((u64)__float_as_uint(ptB) << 32) | (u32)mB;
            }
        }
    }
    __syncthreads();   // #2: local/denom atomics + s_sel complete

    // ---- phase V: combine + exact retrieved + write (wave w = row w) ----
    {
        const int r = w;
        float lv = s_local[r][lane] / s_denom[r];
        // read all 32 (pt, m) pairs (broadcast LDS), batch the 32 gathers
        float pts[32];
        int   ms[32];
        #pragma unroll
        for (int i = 0; i < 32; ++i) {
            u64 s0 = s_sel[r][i];
            pts[i] = __uint_as_float((u32)(s0 >> 32));
            ms[i]  = (int)(u32)(s0 & 0xffffffffu);
        }
        const float* knb2 = kn + (size_t)b * L_ * DH_ + lane;
        float kvv[32];
        #pragma unroll
        for (int i = 0; i < 32; ++i) kvv[i] = knb2[(size_t)ms[i] * DH_];
        float rs = 0.f, ret = 0.f;
        #pragma unroll
        for (int i = 0; i < 16; ++i) {
            rs  += pts[2*i] + pts[2*i+1];
            ret += pts[2*i] * kvv[2*i] + pts[2*i+1] * kvv[2*i+1];
        }
        attn[((size_t)(b * L_ + l0 + r)) * DM_ + h * DH_ + lane] = lv + ret / rs;
    }
}

// ---------------------------------------------------------------------------
extern "C" void kernel_launch(void* const* d_in, const int* in_sizes, int n_in,
                              void* d_out, int out_size, void* d_ws, size_t ws_size,
                              hipStream_t stream) {
    const float* q_in     = (const float*)d_in[0];
    const float* kv_in    = (const float*)d_in[1];
    const float* w_q      = (const float*)d_in[2];
    const float* w_kv     = (const float*)d_in[3];
    const float* w_concat = (const float*)d_in[4];
    float* out = (float*)d_out;

    float* ws   = (float*)d_ws;
    float* q    = ws;                    // 4,194,304 f
    float* attn = ws + 4194304;          // 4,194,304 f
    float* kv   = attn;                  // aliased: kv dead before attn written
    float* kn   = ws + 8388608;          // 262,144 f
    float* invn = ws + 8650752;          // 256 f
    __bf16* bfbase = (__bf16*)(ws + 8651008);
    __bf16* kh  = bfbase;                // 262,144 bf16
    __bf16* vT  = bfbase + 262144;       // 262,144 bf16  (b, 64, 2048)

    gemm128<<<dim3(DM_ / 128, (B_ * L_) / 128), 256, 0, stream>>>(q_in, w_q, q, DM_, DM_);
    gemm64<<<dim3(128 / 64, (B_ * L_) / 64), 256, 0, stream>>>(kv_in, w_kv, kv, 128, DM_);
    col_norms<<<B_ * 128, 256, 0, stream>>>(kv, invn);
    scale_kv<<<dim3(L_ / 64, B_), 256, 0, stream>>>(kv, invn, kn, kh, vT);
    attn_topk<<<dim3(L_ / 16, NH_, B_), 1024, 0, stream>>>(q, kn, kh, vT, attn);
    gemm128<<<dim3(DM_ / 128, (B_ * L_) / 128), 256, 0, stream>>>(attn, w_concat, out, DM_, DM_);
}

// Round 6
// 998.779 us; speedup vs baseline: 1.0577x; 1.0577x over previous
//
#include <hip/hip_runtime.h>
#include <cstddef>
#include <cstring>

#define B_    2
#define L_    2048
#define DM_   1024
#define NH_   16
#define DH_   64
#define SCALE_ 0.125f   // 1/sqrt(64)

typedef __bf16 bf16x8 __attribute__((ext_vector_type(8)));
typedef float  f32x4  __attribute__((ext_vector_type(4)));
typedef unsigned short ushort8v __attribute__((ext_vector_type(8)));
typedef unsigned short ushort4v __attribute__((ext_vector_type(4)));
typedef unsigned long long u64;
typedef unsigned int u32;

__device__ __forceinline__ u32 flipf(float f) {
    u32 u = __float_as_uint(f);
    return (u & 0x80000000u) ? ~u : (u | 0x80000000u);
}
__device__ __forceinline__ float unflipf(u32 k) {
    u32 u = (k & 0x80000000u) ? (k ^ 0x80000000u) : ~k;
    return __uint_as_float(u);
}
__device__ __forceinline__ float bf2f(unsigned short u) {
    return __uint_as_float(((u32)u) << 16);
}
__device__ __forceinline__ unsigned short f2bf(float f) {
    __bf16 h = (__bf16)f;
    unsigned short u;
    __builtin_memcpy(&u, &h, 2);
    return u;
}

// ---------------------------------------------------------------------------
// Weight prep: W (K x N) fp32 -> transposed 3-level bf16 split wt1/2/3 (N x K)
// ---------------------------------------------------------------------------
__global__ __launch_bounds__(256)
void wsplit3(const float* __restrict__ W, unsigned short* __restrict__ w1,
             unsigned short* __restrict__ w2, unsigned short* __restrict__ w3,
             int K, int N) {
    const int n0 = blockIdx.x << 6;
    const int k0 = blockIdx.y << 6;
    const int t  = threadIdx.x;
    __shared__ float s[64][65];
    const int rr = t >> 4;          // 0..15
    const int c4 = (t & 15) << 2;   // 0..60
    #pragma unroll
    for (int rep = 0; rep < 4; ++rep) {
        int k = rr + (rep << 4);
        float4 x = *(const float4*)(W + (size_t)(k0 + k) * N + n0 + c4);
        s[k][c4+0] = x.x; s[k][c4+1] = x.y; s[k][c4+2] = x.z; s[k][c4+3] = x.w;
    }
    __syncthreads();
    #pragma unroll
    for (int rep = 0; rep < 4; ++rep) {
        int n = rr + (rep << 4);
        ushort4v h, m, l;
        #pragma unroll
        for (int j = 0; j < 4; ++j) {
            float x = s[c4 + j][n];
            unsigned short hh = f2bf(x);
            float r = x - bf2f(hh);
            unsigned short mm = f2bf(r);
            float r2 = r - bf2f(mm);
            h[j] = hh; m[j] = mm; l[j] = f2bf(r2);
        }
        size_t o = (size_t)(n0 + n) * K + k0 + c4;
        *(ushort4v*)(w1 + o) = h;
        *(ushort4v*)(w2 + o) = m;
        *(ushort4v*)(w3 + o) = l;
    }
}

// ---------------------------------------------------------------------------
// GEMM via 6-product triple-split bf16 MFMA: C(MxN) = A(MxK) @ W(KxN),
// W pre-transposed+split to wt[n][k] bf16 x3.  Error ~1e-6 (fp32-class).
// Tile M128 x N64, BK=32, 256 thr = 4 waves (2x2 -> 64x32 each).
// ---------------------------------------------------------------------------
__global__ __launch_bounds__(256)
void gemm6p(const float* __restrict__ A, const unsigned short* __restrict__ w1,
            const unsigned short* __restrict__ w2, const unsigned short* __restrict__ w3,
            float* __restrict__ C, int N, int K) {
    __shared__ __align__(16) unsigned short sA[3][128][40];
    __shared__ __align__(16) unsigned short sW[3][64][40];
    const int t    = threadIdx.x;
    const int wv   = t >> 6;
    const int lane = t & 63;
    const int quad = lane >> 4;
    const int n15  = lane & 15;
    const int bm = blockIdx.y << 7;
    const int bn = blockIdx.x << 6;
    const int wm = (wv >> 1) << 6;   // 0 / 64
    const int wn = (wv & 1) << 5;    // 0 / 32
    f32x4 acc[4][2];
    #pragma unroll
    for (int i = 0; i < 4; ++i)
        #pragma unroll
        for (int j = 0; j < 2; ++j)
            #pragma unroll
            for (int r = 0; r < 4; ++r) acc[i][j][r] = 0.f;

    const int ar  = t >> 1,  acg = (t & 1) << 4;   // A: 128 rows x 32 cols
    const int wr  = t >> 2,  wcg = (t & 3) << 3;   // W: 64 rows x 32 cols
    const float* Ap = A + (size_t)(bm + ar) * K + acg;
    const size_t wo = (size_t)(bn + wr) * K + wcg;

    for (int k0 = 0; k0 < K; k0 += 32) {
        float4 a0 = *(const float4*)(Ap + k0);
        float4 a1 = *(const float4*)(Ap + k0 + 4);
        float4 a2 = *(const float4*)(Ap + k0 + 8);
        float4 a3 = *(const float4*)(Ap + k0 + 12);
        ushort8v u1 = *(const ushort8v*)(w1 + wo + k0);
        ushort8v u2 = *(const ushort8v*)(w2 + wo + k0);
        ushort8v u3 = *(const ushort8v*)(w3 + wo + k0);
        __syncthreads();
        {
            float av[16] = {a0.x,a0.y,a0.z,a0.w, a1.x,a1.y,a1.z,a1.w,
                            a2.x,a2.y,a2.z,a2.w, a3.x,a3.y,a3.z,a3.w};
            ushort8v h0, h1, m0, m1, lo0, lo1;
            #pragma unroll
            for (int i = 0; i < 8; ++i) {
                float x = av[i];
                unsigned short hh = f2bf(x);
                float r = x - bf2f(hh);
                unsigned short mm = f2bf(r);
                h0[i] = hh; m0[i] = mm; lo0[i] = f2bf(r - bf2f(mm));
                float y = av[8 + i];
                unsigned short hh2 = f2bf(y);
                float r2 = y - bf2f(hh2);
                unsigned short mm2 = f2bf(r2);
                h1[i] = hh2; m1[i] = mm2; lo1[i] = f2bf(r2 - bf2f(mm2));
            }
            *(ushort8v*)&sA[0][ar][acg]     = h0;
            *(ushort8v*)&sA[0][ar][acg + 8] = h1;
            *(ushort8v*)&sA[1][ar][acg]     = m0;
            *(ushort8v*)&sA[1][ar][acg + 8] = m1;
            *(ushort8v*)&sA[2][ar][acg]     = lo0;
            *(ushort8v*)&sA[2][ar][acg + 8] = lo1;
            *(ushort8v*)&sW[0][wr][wcg] = u1;
            *(ushort8v*)&sW[1][wr][wcg] = u2;
            *(ushort8v*)&sW[2][wr][wcg] = u3;
        }
        __syncthreads();
        bf16x8 af[3][4];
        #pragma unroll
        for (int mi = 0; mi < 4; ++mi) {
            af[0][mi] = *(const bf16x8*)&sA[0][wm + (mi << 4) + n15][quad << 3];
            af[1][mi] = *(const bf16x8*)&sA[1][wm + (mi << 4) + n15][quad << 3];
            af[2][mi] = *(const bf16x8*)&sA[2][wm + (mi << 4) + n15][quad << 3];
        }
        #pragma unroll
        for (int nj = 0; nj < 2; ++nj) {
            bf16x8 wf1 = *(const bf16x8*)&sW[0][wn + (nj << 4) + n15][quad << 3];
            bf16x8 wf2 = *(const bf16x8*)&sW[1][wn + (nj << 4) + n15][quad << 3];
            bf16x8 wf3 = *(const bf16x8*)&sW[2][wn + (nj << 4) + n15][quad << 3];
            #pragma unroll
            for (int mi = 0; mi < 4; ++mi) {
                acc[mi][nj] = __builtin_amdgcn_mfma_f32_16x16x32_bf16(af[0][mi], wf1, acc[mi][nj], 0, 0, 0);
                acc[mi][nj] = __builtin_amdgcn_mfma_f32_16x16x32_bf16(af[0][mi], wf2, acc[mi][nj], 0, 0, 0);
                acc[mi][nj] = __builtin_amdgcn_mfma_f32_16x16x32_bf16(af[1][mi], wf1, acc[mi][nj], 0, 0, 0);
                acc[mi][nj] = __builtin_amdgcn_mfma_f32_16x16x32_bf16(af[1][mi], wf2, acc[mi][nj], 0, 0, 0);
                acc[mi][nj] = __builtin_amdgcn_mfma_f32_16x16x32_bf16(af[0][mi], wf3, acc[mi][nj], 0, 0, 0);
                acc[mi][nj] = __builtin_amdgcn_mfma_f32_16x16x32_bf16(af[2][mi], wf1, acc[mi][nj], 0, 0, 0);
            }
        }
    }
    #pragma unroll
    for (int mi = 0; mi < 4; ++mi)
        #pragma unroll
        for (int nj = 0; nj < 2; ++nj)
            #pragma unroll
            for (int r = 0; r < 4; ++r)
                C[(size_t)(bm + wm + (mi << 4) + (quad << 2) + r) * N
                  + bn + wn + (nj << 4) + n15] = acc[mi][nj][r];
}

// ---------------------------------------------------------------------------
// Column (sequence-axis) L2 norms of kv -> inv_norm[b][c]
// ---------------------------------------------------------------------------
__global__ __launch_bounds__(256)
void col_norms(const float* __restrict__ kv, float* __restrict__ invn) {
    const int bc = blockIdx.x;
    const int b  = bc >> 7;
    const int c  = bc & 127;
    const int t  = threadIdx.x;
    const float* base = kv + (size_t)b * L_ * 128 + c;
    float ss = 0.f;
    for (int l = t; l < L_; l += 256) {
        float x = base[(size_t)l * 128];
        ss += x * x;
    }
    #pragma unroll
    for (int off = 32; off; off >>= 1) ss += __shfl_xor(ss, off);
    __shared__ float red[4];
    if ((t & 63) == 0) red[t >> 6] = ss;
    __syncthreads();
    if (t == 0) {
        float tot = red[0] + red[1] + red[2] + red[3];
        invn[bc] = 1.f / fmaxf(sqrtf(tot), 1e-12f);
    }
}

// ---------------------------------------------------------------------------
// Scale kv by inv-norms: kn fp32 (b,l,64), kh bf16 (b,l,64), vT bf16 (b,64,l)
// ---------------------------------------------------------------------------
__global__ __launch_bounds__(256)
void scale_kv(const float* __restrict__ kv, const float* __restrict__ invn,
              float* __restrict__ kn, __bf16* __restrict__ kh,
              __bf16* __restrict__ vT) {
    const int b  = blockIdx.y;
    const int l0 = blockIdx.x << 6;
    const int t  = threadIdx.x;
    __shared__ float s_inv[128];
    __shared__ float s_vt[64][65];
    if (t < 128) s_inv[t] = invn[b * 128 + t];
    __syncthreads();
    #pragma unroll
    for (int rep = 0; rep < 8; ++rep) {
        int idx = (rep << 8) + t;
        int li  = idx >> 5;
        int c4  = (idx & 31) << 2;
        float4 x = *(const float4*)(kv + ((size_t)(b * L_ + l0 + li)) * 128 + c4);
        x.x *= s_inv[c4]; x.y *= s_inv[c4+1]; x.z *= s_inv[c4+2]; x.w *= s_inv[c4+3];
        if (c4 < 64) {
            size_t o = ((size_t)(b * L_ + l0 + li)) * DH_ + c4;
            *(float4*)(kn + o) = x;
            kh[o+0] = (__bf16)x.x; kh[o+1] = (__bf16)x.y;
            kh[o+2] = (__bf16)x.z; kh[o+3] = (__bf16)x.w;
        } else {
            int d = c4 - 64;
            s_vt[d+0][li] = x.x; s_vt[d+1][li] = x.y; s_vt[d+2][li] = x.z; s_vt[d+3][li] = x.w;
        }
    }
    __syncthreads();
    #pragma unroll
    for (int rep = 0; rep < 4; ++rep) {
        int idx = (rep << 8) + t;
        int d   = idx >> 4;
        int j   = (idx & 15) << 2;
        size_t o = ((size_t)b * DH_ + d) * L_ + l0 + j;
        vT[o+0] = (__bf16)s_vt[d][j+0];
        vT[o+1] = (__bf16)s_vt[d][j+1];
        vT[o+2] = (__bf16)s_vt[d][j+2];
        vT[o+3] = (__bf16)s_vt[d][j+3];
    }
}

// ---------------------------------------------------------------------------
// Kernel A: sims MFMA + threshold/compact (candidates -> global) + local MFMA.
// Writes local/denom quotient into attn; kernel B adds retrieved.
// ---------------------------------------------------------------------------
#define SSTRIDE_ 2072

__global__ __launch_bounds__(1024)
void attn_local(const float* __restrict__ q,    // (B, L, 1024) fp32
                const __bf16* __restrict__ kh,  // (B, L, 64)  bf16
                const __bf16* __restrict__ vT,  // (B, 64, L)  bf16
                float* __restrict__ attn,       // (B, L, 1024): local part
                unsigned short* __restrict__ cand,  // (B*NH*L, 128)
                int* __restrict__ candC) {          // (B*NH*L)
    const int l0   = blockIdx.x << 4;
    const int h    = blockIdx.y;
    const int b    = blockIdx.z;
    const int t    = threadIdx.x;
    const int w    = t >> 6;
    const int lane = t & 63;
    const int quad = lane >> 4;
    const int n15  = lane & 15;

    __shared__ unsigned short s_sims[16 * SSTRIDE_];   // 66,304 B
    __shared__ float s_denom[16];
    __shared__ float s_local[16][66];

    {
        float* sl = &s_local[0][0];
        for (int i = t; i < 16 * 66; i += 1024) sl[i] = 0.f;
        if (t < 16) s_denom[t] = 0.f;
    }

    // ---- phase S: sims via bf16 MFMA (wave w -> m in [128w,128w+128)) ----
    {
        bf16x8 qf[2];
        const float* qp = q + ((size_t)(b * L_ + l0 + n15)) * DM_ + h * DH_ + (quad << 3);
        #pragma unroll
        for (int ks = 0; ks < 2; ++ks) {
            float4 x0 = *(const float4*)(qp + (ks << 5));
            float4 x1 = *(const float4*)(qp + (ks << 5) + 4);
            float xv[8] = {x0.x, x0.y, x0.z, x0.w, x1.x, x1.y, x1.z, x1.w};
            #pragma unroll
            for (int i2 = 0; i2 < 8; ++i2) qf[ks][i2] = (__bf16)xv[i2];
        }
        const __bf16* khb = kh + (size_t)b * L_ * DH_ + (size_t)((w << 7) + n15) * DH_ + (quad << 3);
        #pragma unroll 2
        for (int j = 0; j < 8; ++j) {
            bf16x8 k0 = *(const bf16x8*)(khb + (size_t)(j << 4) * DH_);
            bf16x8 k1 = *(const bf16x8*)(khb + (size_t)(j << 4) * DH_ + 32);
            int m0 = (w << 7) + (j << 4);
            f32x4 acc = {0.f, 0.f, 0.f, 0.f};
            acc = __builtin_amdgcn_mfma_f32_16x16x32_bf16(qf[0], k0, acc, 0, 0, 0);
            acc = __builtin_amdgcn_mfma_f32_16x16x32_bf16(qf[1], k1, acc, 0, 0, 0);
            #pragma unroll
            for (int rr = 0; rr < 4; ++rr)
                s_sims[((quad << 2) + rr) * SSTRIDE_ + m0 + n15] = f2bf(acc[rr]);
        }
    }
    __syncthreads();   // #1

    // ---- phase T: threshold scan + candidate compaction -> global ----
    {
        const int r = w;
        const int rg = ((b * NH_ + h) * L_) + l0 + r;     // global row id
        const unsigned short* srow = s_sims + r * SSTRIDE_;
        ushort8v rv[4];
        #pragma unroll
        for (int j = 0; j < 4; ++j)
            rv[j] = *(const ushort8v*)(srow + (j << 9) + (lane << 3));
        float bv = -3e38f;
        #pragma unroll
        for (int j = 0; j < 4; ++j)
            #pragma unroll
            for (int e = 0; e < 8; ++e) bv = fmaxf(bv, bf2f(rv[j][e]));
        u32 key = flipf(bv);
        u32 thr = 0;
        #pragma unroll
        for (int bp = 31; bp >= 0; --bp) {
            u32 tt = thr | (1u << bp);
            if (__popcll(__ballot(key >= tt)) >= 32) thr = tt;
        }
        float thrv = unflipf(thr) - 0.01f;
        int base = 0;
        unsigned short* cr = cand + (size_t)rg * 128;
        #pragma unroll
        for (int j = 0; j < 4; ++j) {
            #pragma unroll
            for (int e = 0; e < 8; ++e) {
                bool pred = bf2f(rv[j][e]) >= thrv;
                u64 mk = __ballot(pred);
                if (pred) {
                    int pos = base + __popcll(mk & ((1ull << lane) - 1));
                    if (pos < 128)
                        cr[pos] = (unsigned short)((j << 9) + (lane << 3) + e);
                }
                base += __popcll(mk);
            }
        }
        if (lane == 0) candC[rg] = base < 128 ? base : 128;
    }

    // ---- phase L1: local = exp(s*scale) @ v, bf16 MFMA ----
    {
        f32x4 accL[4] = {{0,0,0,0},{0,0,0,0},{0,0,0,0},{0,0,0,0}};
        float psum = 0.f;
        const __bf16* vtb = vT + (size_t)b * DH_ * L_;
        bf16x8 bvv[4][4];
        #pragma unroll
        for (int ks = 0; ks < 4; ++ks) {
            int mb = (w << 7) + (ks << 5);
            #pragma unroll
            for (int nn = 0; nn < 4; ++nn)
                bvv[ks][nn] = *(const bf16x8*)(vtb + (size_t)((nn << 4) + n15) * L_ + mb + (quad << 3));
        }
        #pragma unroll
        for (int ks = 0; ks < 4; ++ks) {
            int mb = (w << 7) + (ks << 5);
            ushort8v pu = *(const ushort8v*)(s_sims + n15 * SSTRIDE_ + mb + (quad << 3));
            bf16x8 af;
            #pragma unroll
            for (int e = 0; e < 8; ++e) {
                float p = __expf(SCALE_ * bf2f(pu[e]));
                psum += p;
                af[e] = (__bf16)p;
            }
            #pragma unroll
            for (int nn = 0; nn < 4; ++nn)
                accL[nn] = __builtin_amdgcn_mfma_f32_16x16x32_bf16(af, bvv[ks][nn], accL[nn], 0, 0, 0);
        }
        psum += __shfl_xor(psum, 16);
        psum += __shfl_xor(psum, 32);
        if (lane < 16) atomicAdd(&s_denom[lane], psum);
        #pragma unroll
        for (int nn = 0; nn < 4; ++nn)
            #pragma unroll
            for (int rr = 0; rr < 4; ++rr)
                atomicAdd(&s_local[(quad << 2) + rr][(nn << 4) + n15], accL[nn][rr]);
    }
    __syncthreads();   // #2

    // ---- combine: write local/denom into attn ----
    {
        const int r = w;
        float lv = s_local[r][lane] / s_denom[r];
        attn[((size_t)(b * L_ + l0 + r)) * DM_ + h * DH_ + lane] = lv;
    }
}

// ---------------------------------------------------------------------------
// Kernel B: exact fp32 refine of candidates + ballot radix top-32 +
// retrieved; adds into attn.  One wave per row, 4 rows/block, no barriers.
// ---------------------------------------------------------------------------
__global__ __launch_bounds__(256)
void topk_retrieve(const float* __restrict__ q, const float* __restrict__ kn,
                   const unsigned short* __restrict__ cand,
                   const int* __restrict__ candC, float* __restrict__ attn) {
    const int wv   = threadIdx.x >> 6;
    const int lane = threadIdx.x & 63;
    const int row  = (blockIdx.x << 2) + wv;
    const int l = row & (L_ - 1);
    const int h = (row >> 11) & (NH_ - 1);
    const int b = row >> 15;
    __shared__ __align__(16) u64 s_sel[4][32];

    const int C = candC[row];
    const unsigned short* cr = cand + (size_t)row * 128;
    const float* knb = kn + (size_t)b * L_ * DH_;
    const float* qr  = q + ((size_t)(b * L_ + l)) * DM_ + h * DH_;

    int mA = (lane < C) ? (int)cr[lane] : 0;
    float dotA;
    {
        const float* kr = knb + (size_t)mA * DH_;
        float4 kx[16];
        #pragma unroll
        for (int d4 = 0; d4 < 16; ++d4) kx[d4] = *(const float4*)(kr + (d4 << 2));
        float dot = 0.f;
        #pragma unroll
        for (int d4 = 0; d4 < 16; ++d4) {
            float4 qx = *(const float4*)(qr + (d4 << 2));
            dot += kx[d4].x * qx.x + kx[d4].y * qx.y + kx[d4].z * qx.z + kx[d4].w * qx.w;
        }
        dotA = dot;
    }
    u32 keyA = (lane < C) ? flipf(dotA) : 0u;
    if (C <= 64) {
        u32 thr2 = 0;
        #pragma unroll
        for (int bp = 31; bp >= 0; --bp) {
            u32 tt = thr2 | (1u << bp);
            if (__popcll(__ballot(keyA >= tt)) >= 32) thr2 = tt;
        }
        bool pred = keyA >= thr2;
        u64 mk = __ballot(pred);
        float pt = __expf(SCALE_ * dotA);
        if (pred) {
            int pos = __popcll(mk & ((1ull << lane) - 1));
            if (pos < 32)
                s_sel[wv][pos] = ((u64)__float_as_uint(pt) << 32) | (u32)mA;
        }
    } else {
        int mB = (64 + lane < C) ? (int)cr[64 + lane] : 0;
        float dotB;
        {
            const float* kr = knb + (size_t)mB * DH_;
            float4 kx[16];
            #pragma unroll
            for (int d4 = 0; d4 < 16; ++d4) kx[d4] = *(const float4*)(kr + (d4 << 2));
            float dot = 0.f;
            #pragma unroll
            for (int d4 = 0; d4 < 16; ++d4) {
                float4 qx = *(const float4*)(qr + (d4 << 2));
                dot += kx[d4].x * qx.x + kx[d4].y * qx.y + kx[d4].z * qx.z + kx[d4].w * qx.w;
            }
            dotB = dot;
        }
        u32 keyB = (64 + lane < C) ? flipf(dotB) : 0u;
        u32 thr2 = 0;
        #pragma unroll
        for (int bp = 31; bp >= 0; --bp) {
            u32 tt = thr2 | (1u << bp);
            int c2 = __popcll(__ballot(keyA >= tt)) + __popcll(__ballot(keyB >= tt));
            if (c2 >= 32) thr2 = tt;
        }
        bool pA = keyA >= thr2, pB = keyB >= thr2;
        u64 mkA = __ballot(pA);
        u64 mkB = __ballot(pB);
        int cA = __popcll(mkA);
        float ptA = __expf(SCALE_ * dotA);
        float ptB = __expf(SCALE_ * dotB);
        if (pA) {
            int pos = __popcll(mkA & ((1ull << lane) - 1));
            if (pos < 32)
                s_sel[wv][pos] = ((u64)__float_as_uint(ptA) << 32) | (u32)mA;
        }
        if (pB) {
            int pos = cA + __popcll(mkB & ((1ull << lane) - 1));
            if (pos < 32)
                s_sel[wv][pos] = ((u64)__float_as_uint(ptB) << 32) | (u32)mB;
        }
    }
    // retrieved: wave-local (LDS write -> read same wave; compiler waits lgkm)
    {
        float pts[32];
        int   ms[32];
        #pragma unroll
        for (int i = 0; i < 32; ++i) {
            u64 s0 = s_sel[wv][i];
            pts[i] = __uint_as_float((u32)(s0 >> 32));
            ms[i]  = (int)(u32)(s0 & 0xffffffffu);
        }
        const float* knb2 = knb + lane;
        float kvv[32];
        #pragma unroll
        for (int i = 0; i < 32; ++i) kvv[i] = knb2[(size_t)ms[i] * DH_];
        float rs = 0.f, ret = 0.f;
        #pragma unroll
        for (int i = 0; i < 16; ++i) {
            rs  += pts[2*i] + pts[2*i+1];
            ret += pts[2*i] * kvv[2*i] + pts[2*i+1] * kvv[2*i+1];
        }
        size_t oa = ((size_t)(b * L_ + l)) * DM_ + h * DH_ + lane;
        attn[oa] = attn[oa] + ret / rs;
    }
}

// ---------------------------------------------------------------------------
extern "C" void kernel_launch(void* const* d_in, const int* in_sizes, int n_in,
                              void* d_out, int out_size, void* d_ws, size_t ws_size,
                              hipStream_t stream) {
    const float* q_in     = (const float*)d_in[0];
    const float* kv_in    = (const float*)d_in[1];
    const float* w_q      = (const float*)d_in[2];
    const float* w_kv     = (const float*)d_in[3];
    const float* w_concat = (const float*)d_in[4];
    float* out = (float*)d_out;

    float* ws   = (float*)d_ws;
    float* q    = ws;                    // 4,194,304 f
    float* attn = ws + 4194304;          // 4,194,304 f
    float* kv   = attn;                  // aliased: kv dead before attn written
    float* kn   = ws + 8388608;          // 262,144 f
    float* invn = ws + 8650752;          // 256 f
    unsigned short* us = (unsigned short*)(ws + 8651008);
    unsigned short* kh_u  = us;                  // 262,144
    unsigned short* vT_u  = us + 262144;         // 262,144
    unsigned short* wq1   = us + 524288;         // 1,048,576 x3
    unsigned short* wq2   = wq1 + 1048576;
    unsigned short* wq3   = wq2 + 1048576;
    unsigned short* wc1   = wq3 + 1048576;       // 1,048,576 x3
    unsigned short* wc2   = wc1 + 1048576;
    unsigned short* wc3   = wc2 + 1048576;
    unsigned short* wkv1  = wc3 + 1048576;       // 131,072 x3
    unsigned short* wkv2  = wkv1 + 131072;
    unsigned short* wkv3  = wkv2 + 131072;
    unsigned short* cand  = wkv3 + 131072;       // 8,388,608
    int* candC = (int*)(cand + 8388608);         // 65,536
    __bf16* kh = (__bf16*)kh_u;
    __bf16* vT = (__bf16*)vT_u;

    // weight prep (transpose + 3-level bf16 split)
    wsplit3<<<dim3(DM_ / 64, DM_ / 64), 256, 0, stream>>>(w_q, wq1, wq2, wq3, DM_, DM_);
    wsplit3<<<dim3(DM_ / 64, DM_ / 64), 256, 0, stream>>>(w_concat, wc1, wc2, wc3, DM_, DM_);
    wsplit3<<<dim3(128 / 64, DM_ / 64), 256, 0, stream>>>(w_kv, wkv1, wkv2, wkv3, DM_, 128);

    // projections (6-product split-bf16 MFMA, fp32-class accuracy)
    gemm6p<<<dim3(DM_ / 64, (B_ * L_) / 128), 256, 0, stream>>>(q_in, wq1, wq2, wq3, q, DM_, DM_);
    gemm6p<<<dim3(128 / 64, (B_ * L_) / 128), 256, 0, stream>>>(kv_in, wkv1, wkv2, wkv3, kv, 128, DM_);

    col_norms<<<B_ * 128, 256, 0, stream>>>(kv, invn);
    scale_kv<<<dim3(L_ / 64, B_), 256, 0, stream>>>(kv, invn, kn, kh, vT);

    // attention: A (sims + candidates + local) then B (refine + retrieved)
    attn_local<<<dim3(L_ / 16, NH_, B_), 1024, 0, stream>>>(q, kh, vT, attn, cand, candC);
    topk_retrieve<<<(B_ * NH_ * L_) / 4, 256, 0, stream>>>(q, kn, cand, candC, attn);

    // output projection
    gemm6p<<<dim3(DM_ / 64, (B_ * L_) / 128), 256, 0, stream>>>(attn, wc1, wc2, wc3, out, DM_, DM_);
}

// Round 7
// 825.966 us; speedup vs baseline: 1.2791x; 1.2092x over previous
//
#include <hip/hip_runtime.h>
#include <cstddef>
#include <cstring>

#define B_    2
#define L_    2048
#define DM_   1024
#define NH_   16
#define DH_   64
#define SCALE_ 0.125f   // 1/sqrt(64)

typedef __bf16 bf16x8 __attribute__((ext_vector_type(8)));
typedef float  f32x4  __attribute__((ext_vector_type(4)));
typedef unsigned short ushort8v __attribute__((ext_vector_type(8)));
typedef unsigned short ushort4v __attribute__((ext_vector_type(4)));
typedef unsigned long long u64;
typedef unsigned int u32;

__device__ __forceinline__ u32 flipf(float f) {
    u32 u = __float_as_uint(f);
    return (u & 0x80000000u) ? ~u : (u | 0x80000000u);
}
__device__ __forceinline__ float unflipf(u32 k) {
    u32 u = (k & 0x80000000u) ? (k ^ 0x80000000u) : ~k;
    return __uint_as_float(u);
}
__device__ __forceinline__ float bf2f(unsigned short u) {
    return __uint_as_float(((u32)u) << 16);
}
__device__ __forceinline__ unsigned short f2bf(float f) {
    __bf16 h = (__bf16)f;
    unsigned short u;
    __builtin_memcpy(&u, &h, 2);
    return u;
}

// ---------------------------------------------------------------------------
// Weight prep: W (K x N) fp32 -> transposed 3-level bf16 split wt1/2/3 (N x K)
// ---------------------------------------------------------------------------
__global__ __launch_bounds__(256)
void wsplit3(const float* __restrict__ W, unsigned short* __restrict__ w1,
             unsigned short* __restrict__ w2, unsigned short* __restrict__ w3,
             int K, int N) {
    const int n0 = blockIdx.x << 6;
    const int k0 = blockIdx.y << 6;
    const int t  = threadIdx.x;
    __shared__ float s[64][65];
    const int rr = t >> 4;
    const int c4 = (t & 15) << 2;
    #pragma unroll
    for (int rep = 0; rep < 4; ++rep) {
        int k = rr + (rep << 4);
        float4 x = *(const float4*)(W + (size_t)(k0 + k) * N + n0 + c4);
        s[k][c4+0] = x.x; s[k][c4+1] = x.y; s[k][c4+2] = x.z; s[k][c4+3] = x.w;
    }
    __syncthreads();
    #pragma unroll
    for (int rep = 0; rep < 4; ++rep) {
        int n = rr + (rep << 4);
        ushort4v h, m, l;
        #pragma unroll
        for (int j = 0; j < 4; ++j) {
            float x = s[c4 + j][n];
            unsigned short hh = f2bf(x);
            float r = x - bf2f(hh);
            unsigned short mm = f2bf(r);
            float r2 = r - bf2f(mm);
            h[j] = hh; m[j] = mm; l[j] = f2bf(r2);
        }
        size_t o = (size_t)(n0 + n) * K + k0 + c4;
        *(ushort4v*)(w1 + o) = h;
        *(ushort4v*)(w2 + o) = m;
        *(ushort4v*)(w3 + o) = l;
    }
}

// ---------------------------------------------------------------------------
// GEMM 6-product triple-split bf16 MFMA (fp32-class): q / kv projections
// ---------------------------------------------------------------------------
__global__ __launch_bounds__(256)
void gemm6p(const float* __restrict__ A, const unsigned short* __restrict__ w1,
            const unsigned short* __restrict__ w2, const unsigned short* __restrict__ w3,
            float* __restrict__ C, int N, int K) {
    __shared__ __align__(16) unsigned short sA[3][128][40];
    __shared__ __align__(16) unsigned short sW[3][64][40];
    const int t    = threadIdx.x;
    const int wv   = t >> 6;
    const int lane = t & 63;
    const int quad = lane >> 4;
    const int n15  = lane & 15;
    const int bm = blockIdx.y << 7;
    const int bn = blockIdx.x << 6;
    const int wm = (wv >> 1) << 6;
    const int wn = (wv & 1) << 5;
    f32x4 acc[4][2];
    #pragma unroll
    for (int i = 0; i < 4; ++i)
        #pragma unroll
        for (int j = 0; j < 2; ++j)
            #pragma unroll
            for (int r = 0; r < 4; ++r) acc[i][j][r] = 0.f;

    const int ar  = t >> 1,  acg = (t & 1) << 4;
    const int wr  = t >> 2,  wcg = (t & 3) << 3;
    const float* Ap = A + (size_t)(bm + ar) * K + acg;
    const size_t wo = (size_t)(bn + wr) * K + wcg;

    for (int k0 = 0; k0 < K; k0 += 32) {
        float4 a0 = *(const float4*)(Ap + k0);
        float4 a1 = *(const float4*)(Ap + k0 + 4);
        float4 a2 = *(const float4*)(Ap + k0 + 8);
        float4 a3 = *(const float4*)(Ap + k0 + 12);
        ushort8v u1 = *(const ushort8v*)(w1 + wo + k0);
        ushort8v u2 = *(const ushort8v*)(w2 + wo + k0);
        ushort8v u3 = *(const ushort8v*)(w3 + wo + k0);
        __syncthreads();
        {
            float av[16] = {a0.x,a0.y,a0.z,a0.w, a1.x,a1.y,a1.z,a1.w,
                            a2.x,a2.y,a2.z,a2.w, a3.x,a3.y,a3.z,a3.w};
            ushort8v h0, h1, m0, m1, lo0, lo1;
            #pragma unroll
            for (int i = 0; i < 8; ++i) {
                float x = av[i];
                unsigned short hh = f2bf(x);
                float r = x - bf2f(hh);
                unsigned short mm = f2bf(r);
                h0[i] = hh; m0[i] = mm; lo0[i] = f2bf(r - bf2f(mm));
                float y = av[8 + i];
                unsigned short hh2 = f2bf(y);
                float r2 = y - bf2f(hh2);
                unsigned short mm2 = f2bf(r2);
                h1[i] = hh2; m1[i] = mm2; lo1[i] = f2bf(r2 - bf2f(mm2));
            }
            *(ushort8v*)&sA[0][ar][acg]     = h0;
            *(ushort8v*)&sA[0][ar][acg + 8] = h1;
            *(ushort8v*)&sA[1][ar][acg]     = m0;
            *(ushort8v*)&sA[1][ar][acg + 8] = m1;
            *(ushort8v*)&sA[2][ar][acg]     = lo0;
            *(ushort8v*)&sA[2][ar][acg + 8] = lo1;
            *(ushort8v*)&sW[0][wr][wcg] = u1;
            *(ushort8v*)&sW[1][wr][wcg] = u2;
            *(ushort8v*)&sW[2][wr][wcg] = u3;
        }
        __syncthreads();
        bf16x8 af[3][4];
        #pragma unroll
        for (int mi = 0; mi < 4; ++mi) {
            af[0][mi] = *(const bf16x8*)&sA[0][wm + (mi << 4) + n15][quad << 3];
            af[1][mi] = *(const bf16x8*)&sA[1][wm + (mi << 4) + n15][quad << 3];
            af[2][mi] = *(const bf16x8*)&sA[2][wm + (mi << 4) + n15][quad << 3];
        }
        #pragma unroll
        for (int nj = 0; nj < 2; ++nj) {
            bf16x8 wf1 = *(const bf16x8*)&sW[0][wn + (nj << 4) + n15][quad << 3];
            bf16x8 wf2 = *(const bf16x8*)&sW[1][wn + (nj << 4) + n15][quad << 3];
            bf16x8 wf3 = *(const bf16x8*)&sW[2][wn + (nj << 4) + n15][quad << 3];
            #pragma unroll
            for (int mi = 0; mi < 4; ++mi) {
                acc[mi][nj] = __builtin_amdgcn_mfma_f32_16x16x32_bf16(af[0][mi], wf1, acc[mi][nj], 0, 0, 0);
                acc[mi][nj] = __builtin_amdgcn_mfma_f32_16x16x32_bf16(af[0][mi], wf2, acc[mi][nj], 0, 0, 0);
                acc[mi][nj] = __builtin_amdgcn_mfma_f32_16x16x32_bf16(af[1][mi], wf1, acc[mi][nj], 0, 0, 0);
                acc[mi][nj] = __builtin_amdgcn_mfma_f32_16x16x32_bf16(af[1][mi], wf2, acc[mi][nj], 0, 0, 0);
                acc[mi][nj] = __builtin_amdgcn_mfma_f32_16x16x32_bf16(af[0][mi], wf3, acc[mi][nj], 0, 0, 0);
                acc[mi][nj] = __builtin_amdgcn_mfma_f32_16x16x32_bf16(af[2][mi], wf1, acc[mi][nj], 0, 0, 0);
            }
        }
    }
    #pragma unroll
    for (int mi = 0; mi < 4; ++mi)
        #pragma unroll
        for (int nj = 0; nj < 2; ++nj)
            #pragma unroll
            for (int r = 0; r < 4; ++r)
                C[(size_t)(bm + wm + (mi << 4) + (quad << 2) + r) * N
                  + bn + wn + (nj << 4) + n15] = acc[mi][nj][r];
}

// ---------------------------------------------------------------------------
// GEMM 3-product double-split bf16 MFMA (~3e-5 abs): output projection only
// ---------------------------------------------------------------------------
__global__ __launch_bounds__(256)
void gemm3p(const float* __restrict__ A, const unsigned short* __restrict__ w1,
            const unsigned short* __restrict__ w2,
            float* __restrict__ C, int N, int K) {
    __shared__ __align__(16) unsigned short sA[2][128][40];
    __shared__ __align__(16) unsigned short sW[2][64][40];
    const int t    = threadIdx.x;
    const int wv   = t >> 6;
    const int lane = t & 63;
    const int quad = lane >> 4;
    const int n15  = lane & 15;
    const int bm = blockIdx.y << 7;
    const int bn = blockIdx.x << 6;
    const int wm = (wv >> 1) << 6;
    const int wn = (wv & 1) << 5;
    f32x4 acc[4][2];
    #pragma unroll
    for (int i = 0; i < 4; ++i)
        #pragma unroll
        for (int j = 0; j < 2; ++j)
            #pragma unroll
            for (int r = 0; r < 4; ++r) acc[i][j][r] = 0.f;

    const int ar  = t >> 1,  acg = (t & 1) << 4;
    const int wr  = t >> 2,  wcg = (t & 3) << 3;
    const float* Ap = A + (size_t)(bm + ar) * K + acg;
    const size_t wo = (size_t)(bn + wr) * K + wcg;

    for (int k0 = 0; k0 < K; k0 += 32) {
        float4 a0 = *(const float4*)(Ap + k0);
        float4 a1 = *(const float4*)(Ap + k0 + 4);
        float4 a2 = *(const float4*)(Ap + k0 + 8);
        float4 a3 = *(const float4*)(Ap + k0 + 12);
        ushort8v u1 = *(const ushort8v*)(w1 + wo + k0);
        ushort8v u2 = *(const ushort8v*)(w2 + wo + k0);
        __syncthreads();
        {
            float av[16] = {a0.x,a0.y,a0.z,a0.w, a1.x,a1.y,a1.z,a1.w,
                            a2.x,a2.y,a2.z,a2.w, a3.x,a3.y,a3.z,a3.w};
            ushort8v h0, h1, l0v, l1v;
            #pragma unroll
            for (int i = 0; i < 8; ++i) {
                float x = av[i];
                unsigned short hh = f2bf(x);
                h0[i] = hh; l0v[i] = f2bf(x - bf2f(hh));
                float y = av[8 + i];
                unsigned short hh2 = f2bf(y);
                h1[i] = hh2; l1v[i] = f2bf(y - bf2f(hh2));
            }
            *(ushort8v*)&sA[0][ar][acg]     = h0;
            *(ushort8v*)&sA[0][ar][acg + 8] = h1;
            *(ushort8v*)&sA[1][ar][acg]     = l0v;
            *(ushort8v*)&sA[1][ar][acg + 8] = l1v;
            *(ushort8v*)&sW[0][wr][wcg] = u1;
            *(ushort8v*)&sW[1][wr][wcg] = u2;
        }
        __syncthreads();
        bf16x8 af[2][4];
        #pragma unroll
        for (int mi = 0; mi < 4; ++mi) {
            af[0][mi] = *(const bf16x8*)&sA[0][wm + (mi << 4) + n15][quad << 3];
            af[1][mi] = *(const bf16x8*)&sA[1][wm + (mi << 4) + n15][quad << 3];
        }
        #pragma unroll
        for (int nj = 0; nj < 2; ++nj) {
            bf16x8 wf1 = *(const bf16x8*)&sW[0][wn + (nj << 4) + n15][quad << 3];
            bf16x8 wf2 = *(const bf16x8*)&sW[1][wn + (nj << 4) + n15][quad << 3];
            #pragma unroll
            for (int mi = 0; mi < 4; ++mi) {
                acc[mi][nj] = __builtin_amdgcn_mfma_f32_16x16x32_bf16(af[0][mi], wf1, acc[mi][nj], 0, 0, 0);
                acc[mi][nj] = __builtin_amdgcn_mfma_f32_16x16x32_bf16(af[0][mi], wf2, acc[mi][nj], 0, 0, 0);
                acc[mi][nj] = __builtin_amdgcn_mfma_f32_16x16x32_bf16(af[1][mi], wf1, acc[mi][nj], 0, 0, 0);
            }
        }
    }
    #pragma unroll
    for (int mi = 0; mi < 4; ++mi)
        #pragma unroll
        for (int nj = 0; nj < 2; ++nj)
            #pragma unroll
            for (int r = 0; r < 4; ++r)
                C[(size_t)(bm + wm + (mi << 4) + (quad << 2) + r) * N
                  + bn + wn + (nj << 4) + n15] = acc[mi][nj][r];
}

// ---------------------------------------------------------------------------
// Column (sequence-axis) L2 norms of kv -> inv_norm[b][c]
// ---------------------------------------------------------------------------
__global__ __launch_bounds__(256)
void col_norms(const float* __restrict__ kv, float* __restrict__ invn) {
    const int bc = blockIdx.x;
    const int b  = bc >> 7;
    const int c  = bc & 127;
    const int t  = threadIdx.x;
    const float* base = kv + (size_t)b * L_ * 128 + c;
    float ss = 0.f;
    for (int l = t; l < L_; l += 256) {
        float x = base[(size_t)l * 128];
        ss += x * x;
    }
    #pragma unroll
    for (int off = 32; off; off >>= 1) ss += __shfl_xor(ss, off);
    __shared__ float red[4];
    if ((t & 63) == 0) red[t >> 6] = ss;
    __syncthreads();
    if (t == 0) {
        float tot = red[0] + red[1] + red[2] + red[3];
        invn[bc] = 1.f / fmaxf(sqrtf(tot), 1e-12f);
    }
}

// ---------------------------------------------------------------------------
// Scale kv by inv-norms: kn fp32 (b,l,64), kh bf16 (b,l,64), vT bf16 (b,64,l)
// ---------------------------------------------------------------------------
__global__ __launch_bounds__(256)
void scale_kv(const float* __restrict__ kv, const float* __restrict__ invn,
              float* __restrict__ kn, __bf16* __restrict__ kh,
              __bf16* __restrict__ vT) {
    const int b  = blockIdx.y;
    const int l0 = blockIdx.x << 6;
    const int t  = threadIdx.x;
    __shared__ float s_inv[128];
    __shared__ float s_vt[64][65];
    if (t < 128) s_inv[t] = invn[b * 128 + t];
    __syncthreads();
    #pragma unroll
    for (int rep = 0; rep < 8; ++rep) {
        int idx = (rep << 8) + t;
        int li  = idx >> 5;
        int c4  = (idx & 31) << 2;
        float4 x = *(const float4*)(kv + ((size_t)(b * L_ + l0 + li)) * 128 + c4);
        x.x *= s_inv[c4]; x.y *= s_inv[c4+1]; x.z *= s_inv[c4+2]; x.w *= s_inv[c4+3];
        if (c4 < 64) {
            size_t o = ((size_t)(b * L_ + l0 + li)) * DH_ + c4;
            *(float4*)(kn + o) = x;
            kh[o+0] = (__bf16)x.x; kh[o+1] = (__bf16)x.y;
            kh[o+2] = (__bf16)x.z; kh[o+3] = (__bf16)x.w;
        } else {
            int d = c4 - 64;
            s_vt[d+0][li] = x.x; s_vt[d+1][li] = x.y; s_vt[d+2][li] = x.z; s_vt[d+3][li] = x.w;
        }
    }
    __syncthreads();
    #pragma unroll
    for (int rep = 0; rep < 4; ++rep) {
        int idx = (rep << 8) + t;
        int d   = idx >> 4;
        int j   = (idx & 15) << 2;
        size_t o = ((size_t)b * DH_ + d) * L_ + l0 + j;
        vT[o+0] = (__bf16)s_vt[d][j+0];
        vT[o+1] = (__bf16)s_vt[d][j+1];
        vT[o+2] = (__bf16)s_vt[d][j+2];
        vT[o+3] = (__bf16)s_vt[d][j+3];
    }
}

// ---------------------------------------------------------------------------
// attn_part: 256-thr (4-wave) block per 16-row tile; loops over two 1024-m
// halves reusing a 33KB sims buffer. Sims MFMA + per-half threshold/compact
// (cand -> global, cap 96/half) + local MFMA accumulated in registers across
// halves. Local written to attn; topk_merge adds retrieved.
// ---------------------------------------------------------------------------
#define SST2_ 1032   // ushort stride (shift 4 banks/row -> 2-way max on S-writes)

__global__ __launch_bounds__(256, 4)
void attn_part(const float* __restrict__ q,    // (B, L, 1024) fp32
               const __bf16* __restrict__ kh,  // (B, L, 64)  bf16
               const __bf16* __restrict__ vT,  // (B, 64, L)  bf16
               float* __restrict__ attn,       // (B, L, 1024): local part
               unsigned short* __restrict__ cand,  // (B*NH*L, 192)
               int* __restrict__ candC) {          // (B*NH*L, 2)
    const int tile = blockIdx.x;
    const int h    = blockIdx.y;
    const int b    = blockIdx.z;
    const int l0   = tile << 4;
    const int t    = threadIdx.x;
    const int w    = t >> 6;
    const int lane = t & 63;
    const int quad = lane >> 4;
    const int n15  = lane & 15;

    __shared__ unsigned short s_sims[16 * SST2_];   // 33,024 B
    __shared__ float s_local[16][66];
    __shared__ float s_denom[16];
    // total ~37.4 KB -> 4 blocks/CU

    {
        float* sl = &s_local[0][0];
        for (int i = t; i < 16 * 66; i += 256) sl[i] = 0.f;
        if (t < 16) s_denom[t] = 0.f;
    }

    // q A-frags (shared rows for all waves)
    bf16x8 qf[2];
    {
        const float* qp = q + ((size_t)(b * L_ + l0 + n15)) * DM_ + h * DH_ + (quad << 3);
        #pragma unroll
        for (int ks = 0; ks < 2; ++ks) {
            float4 x0 = *(const float4*)(qp + (ks << 5));
            float4 x1 = *(const float4*)(qp + (ks << 5) + 4);
            float xv[8] = {x0.x, x0.y, x0.z, x0.w, x1.x, x1.y, x1.z, x1.w};
            #pragma unroll
            for (int i2 = 0; i2 < 8; ++i2) qf[ks][i2] = (__bf16)xv[i2];
        }
    }

    f32x4 accL[4] = {{0,0,0,0},{0,0,0,0},{0,0,0,0},{0,0,0,0}};
    float psum = 0.f;
    const __bf16* khb = kh + (size_t)b * L_ * DH_;
    const __bf16* vtb = vT + (size_t)b * DH_ * L_;
    const int rg0 = ((b * NH_ + h) * L_) + l0;

    #pragma unroll 1
    for (int hf = 0; hf < 2; ++hf) {
        // ---- S: sims for this half (wave w -> 256-m slab) ----
        #pragma unroll
        for (int g = 0; g < 4; ++g) {
            bf16x8 kf[8];
            const __bf16* kp = khb + (size_t)((hf << 10) + (w << 8) + (g << 6) + n15) * DH_ + (quad << 3);
            #pragma unroll
            for (int jj = 0; jj < 4; ++jj) {
                kf[2*jj]   = *(const bf16x8*)(kp + (size_t)(jj << 4) * DH_);
                kf[2*jj+1] = *(const bf16x8*)(kp + (size_t)(jj << 4) * DH_ + 32);
            }
            #pragma unroll
            for (int jj = 0; jj < 4; ++jj) {
                int m0 = (w << 8) + (g << 6) + (jj << 4);   // LDS col 0..1023
                f32x4 acc = {0.f, 0.f, 0.f, 0.f};
                acc = __builtin_amdgcn_mfma_f32_16x16x32_bf16(qf[0], kf[2*jj],   acc, 0, 0, 0);
                acc = __builtin_amdgcn_mfma_f32_16x16x32_bf16(qf[1], kf[2*jj+1], acc, 0, 0, 0);
                #pragma unroll
                for (int rr = 0; rr < 4; ++rr)
                    s_sims[((quad << 2) + rr) * SST2_ + m0 + n15] = f2bf(acc[rr]);
            }
        }
        __syncthreads();

        // ---- T: rows 4w..4w+3, threshold + compact to global ----
        #pragma unroll 1
        for (int rr2 = 0; rr2 < 4; ++rr2) {
            const int r = (w << 2) + rr2;
            const unsigned short* srow = s_sims + r * SST2_;
            ushort8v rv[2];
            rv[0] = *(const ushort8v*)(srow + (lane << 3));
            rv[1] = *(const ushort8v*)(srow + 512 + (lane << 3));
            float bv = -3e38f;
            #pragma unroll
            for (int j = 0; j < 2; ++j)
                #pragma unroll
                for (int e = 0; e < 8; ++e) bv = fmaxf(bv, bf2f(rv[j][e]));
            u32 key = flipf(bv);
            u32 thr = 0;
            #pragma unroll
            for (int bp = 31; bp >= 0; --bp) {
                u32 tt = thr | (1u << bp);
                if (__popcll(__ballot(key >= tt)) >= 32) thr = tt;
            }
            float thrv = unflipf(thr) - 0.01f;
            int base = 0;
            unsigned short* cr = cand + (size_t)(rg0 + r) * 192 + hf * 96;
            #pragma unroll
            for (int j = 0; j < 2; ++j) {
                #pragma unroll
                for (int e = 0; e < 8; ++e) {
                    bool pred = bf2f(rv[j][e]) >= thrv;
                    u64 mk = __ballot(pred);
                    if (pred) {
                        int pos = base + __popcll(mk & ((1ull << lane) - 1));
                        if (pos < 96)
                            cr[pos] = (unsigned short)((hf << 10) + (j << 9) + (lane << 3) + e);
                    }
                    base += __popcll(mk);
                }
            }
            if (lane == 0) candC[((rg0 + r) << 1) + hf] = base < 96 ? base : 96;
        }

        // ---- L1: p@v for this half (wave w: its 256-k slab), acc in regs ----
        #pragma unroll
        for (int g = 0; g < 4; ++g) {
            bf16x8 bvv[2][4];
            #pragma unroll
            for (int t2 = 0; t2 < 2; ++t2)
                #pragma unroll
                for (int nn = 0; nn < 4; ++nn)
                    bvv[t2][nn] = *(const bf16x8*)(vtb + (size_t)((nn << 4) + n15) * L_
                                  + (hf << 10) + (w << 8) + (g << 6) + (t2 << 5) + (quad << 3));
            #pragma unroll
            for (int t2 = 0; t2 < 2; ++t2) {
                int mb = (w << 8) + (g << 6) + (t2 << 5);
                ushort8v pu = *(const ushort8v*)(s_sims + n15 * SST2_ + mb + (quad << 3));
                bf16x8 af;
                #pragma unroll
                for (int e = 0; e < 8; ++e) {
                    float p = __expf(SCALE_ * bf2f(pu[e]));
                    psum += p;
                    af[e] = (__bf16)p;
                }
                #pragma unroll
                for (int nn = 0; nn < 4; ++nn)
                    accL[nn] = __builtin_amdgcn_mfma_f32_16x16x32_bf16(af, bvv[t2][nn], accL[nn], 0, 0, 0);
            }
        }
        __syncthreads();   // sims consumed; next half may overwrite
    }

    // ---- reduce across the 4 waves ----
    psum += __shfl_xor(psum, 16);
    psum += __shfl_xor(psum, 32);
    if (lane < 16) atomicAdd(&s_denom[lane], psum);
    #pragma unroll
    for (int nn = 0; nn < 4; ++nn)
        #pragma unroll
        for (int rr = 0; rr < 4; ++rr)
            atomicAdd(&s_local[(quad << 2) + rr][(nn << 4) + n15], accL[nn][rr]);
    __syncthreads();

    // ---- write local part into attn ----
    {
        int r  = t >> 4;
        int d0 = (t & 15) << 2;
        float inv = 1.f / s_denom[r];
        float* op = attn + ((size_t)(b * L_ + l0 + r)) * DM_ + h * DH_ + d0;
        op[0] = s_local[r][d0+0] * inv;
        op[1] = s_local[r][d0+1] * inv;
        op[2] = s_local[r][d0+2] * inv;
        op[3] = s_local[r][d0+3] * inv;
    }
}

// ---------------------------------------------------------------------------
// topk_merge: one wave per row; exact fp32 refine of merged candidate list
// (C = c0+c1 <= 192, 1..3 batches) + ballot radix top-32 + retrieved; RMW attn.
// ---------------------------------------------------------------------------
__global__ __launch_bounds__(256)
void topk_merge(const float* __restrict__ q, const float* __restrict__ kn,
                const unsigned short* __restrict__ cand,
                const int* __restrict__ candC, float* __restrict__ attn) {
    const int wv   = threadIdx.x >> 6;
    const int lane = threadIdx.x & 63;
    const int row  = (blockIdx.x << 2) + wv;
    const int l = row & (L_ - 1);
    const int h = (row >> 11) & (NH_ - 1);
    const int b = row >> 15;
    __shared__ __align__(16) u64 s_sel[4][32];

    const int c0 = candC[row << 1];
    const int c1 = candC[(row << 1) + 1];
    const int C  = c0 + c1;           // >= 64
    const int nb = (C + 63) >> 6;     // 1..3
    const unsigned short* cr = cand + (size_t)row * 192;
    const float* knb = kn + (size_t)b * L_ * DH_;
    const float* qr  = q + ((size_t)(b * L_ + l)) * DM_ + h * DH_;

    float4 qx[16];
    #pragma unroll
    for (int d4 = 0; d4 < 16; ++d4) qx[d4] = *(const float4*)(qr + (d4 << 2));

    u32   keyv[3];
    float dotv[3];
    int   mv[3];
    #pragma unroll 1
    for (int bt = 0; bt < nb; ++bt) {
        int i = (bt << 6) + lane;
        bool act = i < C;
        int m = 0;
        if (act) m = (i < c0) ? (int)cr[i] : (int)cr[96 + (i - c0)];
        const float* kr = knb + (size_t)m * DH_;
        float4 kx[16];
        #pragma unroll
        for (int d4 = 0; d4 < 16; ++d4) kx[d4] = *(const float4*)(kr + (d4 << 2));
        float dot = 0.f;
        #pragma unroll
        for (int d4 = 0; d4 < 16; ++d4)
            dot += kx[d4].x * qx[d4].x + kx[d4].y * qx[d4].y
                 + kx[d4].z * qx[d4].z + kx[d4].w * qx[d4].w;
        keyv[bt] = act ? flipf(dot) : 0u;
        dotv[bt] = dot;
        mv[bt]   = m;
    }
    u32 thr2 = 0;
    #pragma unroll 1
    for (int bp = 31; bp >= 0; --bp) {
        u32 tt = thr2 | (1u << bp);
        int c2 = 0;
        for (int bt = 0; bt < nb; ++bt)
            c2 += __popcll(__ballot(keyv[bt] >= tt));
        if (c2 >= 32) thr2 = tt;
    }
    int off = 0;
    #pragma unroll 1
    for (int bt = 0; bt < nb; ++bt) {
        bool pred = keyv[bt] >= thr2;
        u64 mk = __ballot(pred);
        if (pred) {
            int pos = off + __popcll(mk & ((1ull << lane) - 1));
            if (pos < 32) {
                float pt = __expf(SCALE_ * dotv[bt]);
                s_sel[wv][pos] = ((u64)__float_as_uint(pt) << 32) | (u32)mv[bt];
            }
        }
        off += __popcll(mk);
    }
    // retrieved (wave-local: same-wave LDS ordering suffices, no barrier)
    {
        float pts[32];
        int   ms[32];
        #pragma unroll
        for (int i = 0; i < 32; ++i) {
            u64 s0 = s_sel[wv][i];
            pts[i] = __uint_as_float((u32)(s0 >> 32));
            ms[i]  = (int)(u32)(s0 & 0xffffffffu);
        }
        const float* knb2 = knb + lane;
        float kvv[32];
        #pragma unroll
        for (int i = 0; i < 32; ++i) kvv[i] = knb2[(size_t)ms[i] * DH_];
        float rs = 0.f, ret = 0.f;
        #pragma unroll
        for (int i = 0; i < 16; ++i) {
            rs  += pts[2*i] + pts[2*i+1];
            ret += pts[2*i] * kvv[2*i] + pts[2*i+1] * kvv[2*i+1];
        }
        size_t oa = ((size_t)(b * L_ + l)) * DM_ + h * DH_ + lane;
        attn[oa] = attn[oa] + ret / rs;
    }
}

// ---------------------------------------------------------------------------
extern "C" void kernel_launch(void* const* d_in, const int* in_sizes, int n_in,
                              void* d_out, int out_size, void* d_ws, size_t ws_size,
                              hipStream_t stream) {
    const float* q_in     = (const float*)d_in[0];
    const float* kv_in    = (const float*)d_in[1];
    const float* w_q      = (const float*)d_in[2];
    const float* w_kv     = (const float*)d_in[3];
    const float* w_concat = (const float*)d_in[4];
    float* out = (float*)d_out;

    float* ws   = (float*)d_ws;
    float* q    = ws;                    // 4,194,304 f
    float* attn = ws + 4194304;          // 4,194,304 f
    float* kv   = attn;                  // aliased: kv dead before attn written
    float* kn   = ws + 8388608;          // 262,144 f
    float* invn = ws + 8650752;          // 256 f
    unsigned short* us = (unsigned short*)(ws + 8651008);
    unsigned short* kh_u = us;                   // 262,144
    unsigned short* vT_u = us + 262144;          // 262,144
    unsigned short* wq1  = us + 524288;          // 1,048,576 x3
    unsigned short* wq2  = wq1 + 1048576;
    unsigned short* wq3  = wq2 + 1048576;
    unsigned short* wc1  = wq3 + 1048576;        // 1,048,576 x2
    unsigned short* wc2  = wc1 + 1048576;
    unsigned short* wkv1 = wc2 + 1048576;        // 131,072 x3
    unsigned short* wkv2 = wkv1 + 131072;
    unsigned short* wkv3 = wkv2 + 131072;
    unsigned short* cand = wkv3 + 131072;        // 65536*192 = 12,582,912
    unsigned short* wc3  = cand;                 // alias: written then dead before cand
    int* candC = (int*)(cand + 12582912);        // 131,072 ints
    __bf16* kh = (__bf16*)kh_u;
    __bf16* vT = (__bf16*)vT_u;

    // weight prep
    wsplit3<<<dim3(DM_ / 64, DM_ / 64), 256, 0, stream>>>(w_q, wq1, wq2, wq3, DM_, DM_);
    wsplit3<<<dim3(DM_ / 64, DM_ / 64), 256, 0, stream>>>(w_concat, wc1, wc2, wc3, DM_, DM_);
    wsplit3<<<dim3(128 / 64, DM_ / 64), 256, 0, stream>>>(w_kv, wkv1, wkv2, wkv3, DM_, 128);

    // projections
    gemm6p<<<dim3(DM_ / 64, (B_ * L_) / 128), 256, 0, stream>>>(q_in, wq1, wq2, wq3, q, DM_, DM_);
    gemm6p<<<dim3(128 / 64, (B_ * L_) / 128), 256, 0, stream>>>(kv_in, wkv1, wkv2, wkv3, kv, 128, DM_);

    col_norms<<<B_ * 128, 256, 0, stream>>>(kv, invn);
    scale_kv<<<dim3(L_ / 64, B_), 256, 0, stream>>>(kv, invn, kn, kh, vT);

    // attention
    attn_part<<<dim3(L_ / 16, NH_, B_), 256, 0, stream>>>(q, kh, vT, attn, cand, candC);
    topk_merge<<<(B_ * NH_ * L_) / 4, 256, 0, stream>>>(q, kn, cand, candC, attn);

    // output projection (3-product)
    gemm3p<<<dim3(DM_ / 64, (B_ * L_) / 128), 256, 0, stream>>>(attn, wc1, wc2, out, DM_, DM_);
}

// Round 8
// 688.329 us; speedup vs baseline: 1.5348x; 1.2000x over previous
//
#include <hip/hip_runtime.h>
#include <cstddef>
#include <cstring>

#define B_    2
#define L_    2048
#define DM_   1024
#define NH_   16
#define DH_   64
#define SCALE_ 0.125f   // 1/sqrt(64)

typedef __bf16 bf16x8 __attribute__((ext_vector_type(8)));
typedef float  f32x4  __attribute__((ext_vector_type(4)));
typedef unsigned short ushort8v __attribute__((ext_vector_type(8)));
typedef unsigned short ushort4v __attribute__((ext_vector_type(4)));
typedef unsigned long long u64;
typedef unsigned int u32;

__device__ __forceinline__ u32 flipf(float f) {
    u32 u = __float_as_uint(f);
    return (u & 0x80000000u) ? ~u : (u | 0x80000000u);
}
__device__ __forceinline__ float bf2f(unsigned short u) {
    return __uint_as_float(((u32)u) << 16);
}
__device__ __forceinline__ unsigned short f2bf(float f) {
    __bf16 h = (__bf16)f;
    unsigned short u;
    __builtin_memcpy(&u, &h, 2);
    return u;
}
__device__ __forceinline__ u32 flip16(unsigned short u) {
    return (u & 0x8000u) ? (u32)(~u & 0xffffu) : (u32)(u | 0x8000u);
}
__device__ __forceinline__ unsigned short unflip16(u32 k) {
    return (k & 0x8000u) ? (unsigned short)(k ^ 0x8000u) : (unsigned short)(~k & 0xffffu);
}

// ---------------------------------------------------------------------------
// Weight prep: W (K x N) fp32 -> transposed 3-level bf16 split wt1/2/3 (N x K)
// ---------------------------------------------------------------------------
__global__ __launch_bounds__(256)
void wsplit3(const float* __restrict__ W, unsigned short* __restrict__ w1,
             unsigned short* __restrict__ w2, unsigned short* __restrict__ w3,
             int K, int N) {
    const int n0 = blockIdx.x << 6;
    const int k0 = blockIdx.y << 6;
    const int t  = threadIdx.x;
    __shared__ float s[64][65];
    const int rr = t >> 4;
    const int c4 = (t & 15) << 2;
    #pragma unroll
    for (int rep = 0; rep < 4; ++rep) {
        int k = rr + (rep << 4);
        float4 x = *(const float4*)(W + (size_t)(k0 + k) * N + n0 + c4);
        s[k][c4+0] = x.x; s[k][c4+1] = x.y; s[k][c4+2] = x.z; s[k][c4+3] = x.w;
    }
    __syncthreads();
    #pragma unroll
    for (int rep = 0; rep < 4; ++rep) {
        int n = rr + (rep << 4);
        ushort4v h, m, l;
        #pragma unroll
        for (int j = 0; j < 4; ++j) {
            float x = s[c4 + j][n];
            unsigned short hh = f2bf(x);
            float r = x - bf2f(hh);
            unsigned short mm = f2bf(r);
            float r2 = r - bf2f(mm);
            h[j] = hh; m[j] = mm; l[j] = f2bf(r2);
        }
        size_t o = (size_t)(n0 + n) * K + k0 + c4;
        *(ushort4v*)(w1 + o) = h;
        *(ushort4v*)(w2 + o) = m;
        *(ushort4v*)(w3 + o) = l;
    }
}

// ---------------------------------------------------------------------------
// GEMM 6-product triple-split bf16 MFMA (fp32-class): q / kv projections
// ---------------------------------------------------------------------------
__global__ __launch_bounds__(256)
void gemm6p(const float* __restrict__ A, const unsigned short* __restrict__ w1,
            const unsigned short* __restrict__ w2, const unsigned short* __restrict__ w3,
            float* __restrict__ C, int N, int K) {
    __shared__ __align__(16) unsigned short sA[3][128][40];
    __shared__ __align__(16) unsigned short sW[3][64][40];
    const int t    = threadIdx.x;
    const int wv   = t >> 6;
    const int lane = t & 63;
    const int quad = lane >> 4;
    const int n15  = lane & 15;
    const int bm = blockIdx.y << 7;
    const int bn = blockIdx.x << 6;
    const int wm = (wv >> 1) << 6;
    const int wn = (wv & 1) << 5;
    f32x4 acc[4][2];
    #pragma unroll
    for (int i = 0; i < 4; ++i)
        #pragma unroll
        for (int j = 0; j < 2; ++j)
            #pragma unroll
            for (int r = 0; r < 4; ++r) acc[i][j][r] = 0.f;

    const int ar  = t >> 1,  acg = (t & 1) << 4;
    const int wr  = t >> 2,  wcg = (t & 3) << 3;
    const float* Ap = A + (size_t)(bm + ar) * K + acg;
    const size_t wo = (size_t)(bn + wr) * K + wcg;

    for (int k0 = 0; k0 < K; k0 += 32) {
        float4 a0 = *(const float4*)(Ap + k0);
        float4 a1 = *(const float4*)(Ap + k0 + 4);
        float4 a2 = *(const float4*)(Ap + k0 + 8);
        float4 a3 = *(const float4*)(Ap + k0 + 12);
        ushort8v u1 = *(const ushort8v*)(w1 + wo + k0);
        ushort8v u2 = *(const ushort8v*)(w2 + wo + k0);
        ushort8v u3 = *(const ushort8v*)(w3 + wo + k0);
        __syncthreads();
        {
            float av[16] = {a0.x,a0.y,a0.z,a0.w, a1.x,a1.y,a1.z,a1.w,
                            a2.x,a2.y,a2.z,a2.w, a3.x,a3.y,a3.z,a3.w};
            ushort8v h0, h1, m0, m1, lo0, lo1;
            #pragma unroll
            for (int i = 0; i < 8; ++i) {
                float x = av[i];
                unsigned short hh = f2bf(x);
                float r = x - bf2f(hh);
                unsigned short mm = f2bf(r);
                h0[i] = hh; m0[i] = mm; lo0[i] = f2bf(r - bf2f(mm));
                float y = av[8 + i];
                unsigned short hh2 = f2bf(y);
                float r2 = y - bf2f(hh2);
                unsigned short mm2 = f2bf(r2);
                h1[i] = hh2; m1[i] = mm2; lo1[i] = f2bf(r2 - bf2f(mm2));
            }
            *(ushort8v*)&sA[0][ar][acg]     = h0;
            *(ushort8v*)&sA[0][ar][acg + 8] = h1;
            *(ushort8v*)&sA[1][ar][acg]     = m0;
            *(ushort8v*)&sA[1][ar][acg + 8] = m1;
            *(ushort8v*)&sA[2][ar][acg]     = lo0;
            *(ushort8v*)&sA[2][ar][acg + 8] = lo1;
            *(ushort8v*)&sW[0][wr][wcg] = u1;
            *(ushort8v*)&sW[1][wr][wcg] = u2;
            *(ushort8v*)&sW[2][wr][wcg] = u3;
        }
        __syncthreads();
        bf16x8 af[3][4];
        #pragma unroll
        for (int mi = 0; mi < 4; ++mi) {
            af[0][mi] = *(const bf16x8*)&sA[0][wm + (mi << 4) + n15][quad << 3];
            af[1][mi] = *(const bf16x8*)&sA[1][wm + (mi << 4) + n15][quad << 3];
            af[2][mi] = *(const bf16x8*)&sA[2][wm + (mi << 4) + n15][quad << 3];
        }
        #pragma unroll
        for (int nj = 0; nj < 2; ++nj) {
            bf16x8 wf1 = *(const bf16x8*)&sW[0][wn + (nj << 4) + n15][quad << 3];
            bf16x8 wf2 = *(const bf16x8*)&sW[1][wn + (nj << 4) + n15][quad << 3];
            bf16x8 wf3 = *(const bf16x8*)&sW[2][wn + (nj << 4) + n15][quad << 3];
            #pragma unroll
            for (int mi = 0; mi < 4; ++mi) {
                acc[mi][nj] = __builtin_amdgcn_mfma_f32_16x16x32_bf16(af[0][mi], wf1, acc[mi][nj], 0, 0, 0);
                acc[mi][nj] = __builtin_amdgcn_mfma_f32_16x16x32_bf16(af[0][mi], wf2, acc[mi][nj], 0, 0, 0);
                acc[mi][nj] = __builtin_amdgcn_mfma_f32_16x16x32_bf16(af[1][mi], wf1, acc[mi][nj], 0, 0, 0);
                acc[mi][nj] = __builtin_amdgcn_mfma_f32_16x16x32_bf16(af[1][mi], wf2, acc[mi][nj], 0, 0, 0);
                acc[mi][nj] = __builtin_amdgcn_mfma_f32_16x16x32_bf16(af[0][mi], wf3, acc[mi][nj], 0, 0, 0);
                acc[mi][nj] = __builtin_amdgcn_mfma_f32_16x16x32_bf16(af[2][mi], wf1, acc[mi][nj], 0, 0, 0);
            }
        }
    }
    #pragma unroll
    for (int mi = 0; mi < 4; ++mi)
        #pragma unroll
        for (int nj = 0; nj < 2; ++nj)
            #pragma unroll
            for (int r = 0; r < 4; ++r)
                C[(size_t)(bm + wm + (mi << 4) + (quad << 2) + r) * N
                  + bn + wn + (nj << 4) + n15] = acc[mi][nj][r];
}

// ---------------------------------------------------------------------------
// GEMM 3-product double-split bf16 MFMA (~3e-5 abs): output projection only
// ---------------------------------------------------------------------------
__global__ __launch_bounds__(256)
void gemm3p(const float* __restrict__ A, const unsigned short* __restrict__ w1,
            const unsigned short* __restrict__ w2,
            float* __restrict__ C, int N, int K) {
    __shared__ __align__(16) unsigned short sA[2][128][40];
    __shared__ __align__(16) unsigned short sW[2][64][40];
    const int t    = threadIdx.x;
    const int wv   = t >> 6;
    const int lane = t & 63;
    const int quad = lane >> 4;
    const int n15  = lane & 15;
    const int bm = blockIdx.y << 7;
    const int bn = blockIdx.x << 6;
    const int wm = (wv >> 1) << 6;
    const int wn = (wv & 1) << 5;
    f32x4 acc[4][2];
    #pragma unroll
    for (int i = 0; i < 4; ++i)
        #pragma unroll
        for (int j = 0; j < 2; ++j)
            #pragma unroll
            for (int r = 0; r < 4; ++r) acc[i][j][r] = 0.f;

    const int ar  = t >> 1,  acg = (t & 1) << 4;
    const int wr  = t >> 2,  wcg = (t & 3) << 3;
    const float* Ap = A + (size_t)(bm + ar) * K + acg;
    const size_t wo = (size_t)(bn + wr) * K + wcg;

    for (int k0 = 0; k0 < K; k0 += 32) {
        float4 a0 = *(const float4*)(Ap + k0);
        float4 a1 = *(const float4*)(Ap + k0 + 4);
        float4 a2 = *(const float4*)(Ap + k0 + 8);
        float4 a3 = *(const float4*)(Ap + k0 + 12);
        ushort8v u1 = *(const ushort8v*)(w1 + wo + k0);
        ushort8v u2 = *(const ushort8v*)(w2 + wo + k0);
        __syncthreads();
        {
            float av[16] = {a0.x,a0.y,a0.z,a0.w, a1.x,a1.y,a1.z,a1.w,
                            a2.x,a2.y,a2.z,a2.w, a3.x,a3.y,a3.z,a3.w};
            ushort8v h0, h1, l0v, l1v;
            #pragma unroll
            for (int i = 0; i < 8; ++i) {
                float x = av[i];
                unsigned short hh = f2bf(x);
                h0[i] = hh; l0v[i] = f2bf(x - bf2f(hh));
                float y = av[8 + i];
                unsigned short hh2 = f2bf(y);
                h1[i] = hh2; l1v[i] = f2bf(y - bf2f(hh2));
            }
            *(ushort8v*)&sA[0][ar][acg]     = h0;
            *(ushort8v*)&sA[0][ar][acg + 8] = h1;
            *(ushort8v*)&sA[1][ar][acg]     = l0v;
            *(ushort8v*)&sA[1][ar][acg + 8] = l1v;
            *(ushort8v*)&sW[0][wr][wcg] = u1;
            *(ushort8v*)&sW[1][wr][wcg] = u2;
        }
        __syncthreads();
        bf16x8 af[2][4];
        #pragma unroll
        for (int mi = 0; mi < 4; ++mi) {
            af[0][mi] = *(const bf16x8*)&sA[0][wm + (mi << 4) + n15][quad << 3];
            af[1][mi] = *(const bf16x8*)&sA[1][wm + (mi << 4) + n15][quad << 3];
        }
        #pragma unroll
        for (int nj = 0; nj < 2; ++nj) {
            bf16x8 wf1 = *(const bf16x8*)&sW[0][wn + (nj << 4) + n15][quad << 3];
            bf16x8 wf2 = *(const bf16x8*)&sW[1][wn + (nj << 4) + n15][quad << 3];
            #pragma unroll
            for (int mi = 0; mi < 4; ++mi) {
                acc[mi][nj] = __builtin_amdgcn_mfma_f32_16x16x32_bf16(af[0][mi], wf1, acc[mi][nj], 0, 0, 0);
                acc[mi][nj] = __builtin_amdgcn_mfma_f32_16x16x32_bf16(af[0][mi], wf2, acc[mi][nj], 0, 0, 0);
                acc[mi][nj] = __builtin_amdgcn_mfma_f32_16x16x32_bf16(af[1][mi], wf1, acc[mi][nj], 0, 0, 0);
            }
        }
    }
    #pragma unroll
    for (int mi = 0; mi < 4; ++mi)
        #pragma unroll
        for (int nj = 0; nj < 2; ++nj)
            #pragma unroll
            for (int r = 0; r < 4; ++r)
                C[(size_t)(bm + wm + (mi << 4) + (quad << 2) + r) * N
                  + bn + wn + (nj << 4) + n15] = acc[mi][nj][r];
}

// ---------------------------------------------------------------------------
// Column (sequence-axis) L2 norms of kv -> inv_norm[b][c]
// ---------------------------------------------------------------------------
__global__ __launch_bounds__(256)
void col_norms(const float* __restrict__ kv, float* __restrict__ invn) {
    const int bc = blockIdx.x;
    const int b  = bc >> 7;
    const int c  = bc & 127;
    const int t  = threadIdx.x;
    const float* base = kv + (size_t)b * L_ * 128 + c;
    float ss = 0.f;
    for (int l = t; l < L_; l += 256) {
        float x = base[(size_t)l * 128];
        ss += x * x;
    }
    #pragma unroll
    for (int off = 32; off; off >>= 1) ss += __shfl_xor(ss, off);
    __shared__ float red[4];
    if ((t & 63) == 0) red[t >> 6] = ss;
    __syncthreads();
    if (t == 0) {
        float tot = red[0] + red[1] + red[2] + red[3];
        invn[bc] = 1.f / fmaxf(sqrtf(tot), 1e-12f);
    }
}

// ---------------------------------------------------------------------------
// Scale kv by inv-norms: kn fp32 (b,l,64), kh bf16 (b,l,64), vT bf16 (b,64,l)
// ---------------------------------------------------------------------------
__global__ __launch_bounds__(256)
void scale_kv(const float* __restrict__ kv, const float* __restrict__ invn,
              float* __restrict__ kn, __bf16* __restrict__ kh,
              __bf16* __restrict__ vT) {
    const int b  = blockIdx.y;
    const int l0 = blockIdx.x << 6;
    const int t  = threadIdx.x;
    __shared__ float s_inv[128];
    __shared__ float s_vt[64][65];
    if (t < 128) s_inv[t] = invn[b * 128 + t];
    __syncthreads();
    #pragma unroll
    for (int rep = 0; rep < 8; ++rep) {
        int idx = (rep << 8) + t;
        int li  = idx >> 5;
        int c4  = (idx & 31) << 2;
        float4 x = *(const float4*)(kv + ((size_t)(b * L_ + l0 + li)) * 128 + c4);
        x.x *= s_inv[c4]; x.y *= s_inv[c4+1]; x.z *= s_inv[c4+2]; x.w *= s_inv[c4+3];
        if (c4 < 64) {
            size_t o = ((size_t)(b * L_ + l0 + li)) * DH_ + c4;
            *(float4*)(kn + o) = x;
            kh[o+0] = (__bf16)x.x; kh[o+1] = (__bf16)x.y;
            kh[o+2] = (__bf16)x.z; kh[o+3] = (__bf16)x.w;
        } else {
            int d = c4 - 64;
            s_vt[d+0][li] = x.x; s_vt[d+1][li] = x.y; s_vt[d+2][li] = x.z; s_vt[d+3][li] = x.w;
        }
    }
    __syncthreads();
    #pragma unroll
    for (int rep = 0; rep < 4; ++rep) {
        int idx = (rep << 8) + t;
        int d   = idx >> 4;
        int j   = (idx & 15) << 2;
        size_t o = ((size_t)b * DH_ + d) * L_ + l0 + j;
        vT[o+0] = (__bf16)s_vt[d][j+0];
        vT[o+1] = (__bf16)s_vt[d][j+1];
        vT[o+2] = (__bf16)s_vt[d][j+2];
        vT[o+3] = (__bf16)s_vt[d][j+3];
    }
}

// ---------------------------------------------------------------------------
// attn_part (R8): swapped-operand sims MFMA -> packed b64 LDS stores;
// 16-bit radix; full-row threshold via provisional h0 list + h1 filter
// (C ~50 instead of ~100). Local MFMA unchanged. 4-wave blocks, halves.
// ---------------------------------------------------------------------------
#define SST2_ 1032   // ushort row stride (row = 2064 B, 16B-aligned)

__global__ __launch_bounds__(256, 4)
void attn_part(const float* __restrict__ q,    // (B, L, 1024) fp32
               const __bf16* __restrict__ kh,  // (B, L, 64)  bf16
               const __bf16* __restrict__ vT,  // (B, 64, L)  bf16
               float* __restrict__ attn,       // (B, L, 1024): local part
               u32* __restrict__ cand,         // (B*NH*L, 96): (bf16bits<<16)|m
               int* __restrict__ candC) {      // (B*NH*L)
    const int tile = blockIdx.x;
    const int h    = blockIdx.y;
    const int b    = blockIdx.z;
    const int l0   = tile << 4;
    const int t    = threadIdx.x;
    const int w    = t >> 6;
    const int lane = t & 63;
    const int quad = lane >> 4;
    const int n15  = lane & 15;

    __shared__ unsigned short s_sims[16 * SST2_];   // 33,024 B
    __shared__ float s_local[16][66];
    __shared__ float s_denom[16];

    {
        float* sl = &s_local[0][0];
        for (int i = t; i < 16 * 66; i += 256) sl[i] = 0.f;
        if (t < 16) s_denom[t] = 0.f;
    }

    // q fragments (B-operand layout == A-operand layout)
    bf16x8 qf[2];
    {
        const float* qp = q + ((size_t)(b * L_ + l0 + n15)) * DM_ + h * DH_ + (quad << 3);
        #pragma unroll
        for (int ks = 0; ks < 2; ++ks) {
            float4 x0 = *(const float4*)(qp + (ks << 5));
            float4 x1 = *(const float4*)(qp + (ks << 5) + 4);
            float xv[8] = {x0.x, x0.y, x0.z, x0.w, x1.x, x1.y, x1.z, x1.w};
            #pragma unroll
            for (int i2 = 0; i2 < 8; ++i2) qf[ks][i2] = (__bf16)xv[i2];
        }
    }

    f32x4 accL[4] = {{0,0,0,0},{0,0,0,0},{0,0,0,0},{0,0,0,0}};
    float psum = 0.f;
    float bvmax[4] = {-3e38f, -3e38f, -3e38f, -3e38f};  // running full-row lane maxima
    int   c0[4]    = {0, 0, 0, 0};                      // provisional h0 counts
    const __bf16* khb = kh + (size_t)b * L_ * DH_;
    const __bf16* vtb = vT + (size_t)b * DH_ * L_;
    const int rg0 = ((b * NH_ + h) * L_) + l0;

    #pragma unroll 1
    for (int hf = 0; hf < 2; ++hf) {
        // ---- S: sims via swapped-operand MFMA; packed b64 stores ----
        #pragma unroll
        for (int g = 0; g < 4; ++g) {
            bf16x8 kf[8];
            const __bf16* kp = khb + (size_t)((hf << 10) + (w << 8) + (g << 6) + n15) * DH_ + (quad << 3);
            #pragma unroll
            for (int jj = 0; jj < 4; ++jj) {
                kf[2*jj]   = *(const bf16x8*)(kp + (size_t)(jj << 4) * DH_);
                kf[2*jj+1] = *(const bf16x8*)(kp + (size_t)(jj << 4) * DH_ + 32);
            }
            #pragma unroll
            for (int jj = 0; jj < 4; ++jj) {
                int m0 = (w << 8) + (g << 6) + (jj << 4);   // LDS col base
                f32x4 acc = {0.f, 0.f, 0.f, 0.f};
                acc = __builtin_amdgcn_mfma_f32_16x16x32_bf16(kf[2*jj],   qf[0], acc, 0, 0, 0);
                acc = __builtin_amdgcn_mfma_f32_16x16x32_bf16(kf[2*jj+1], qf[1], acc, 0, 0, 0);
                // lane holds rows m0+quad*4+{0..3} for q-row n15 -> packed store
                u32 lo = (u32)f2bf(acc[0]) | ((u32)f2bf(acc[1]) << 16);
                u32 hi = (u32)f2bf(acc[2]) | ((u32)f2bf(acc[3]) << 16);
                u64 pk = ((u64)hi << 32) | lo;
                *(u64*)(s_sims + (size_t)n15 * SST2_ + m0 + (quad << 2)) = pk;
            }
        }
        __syncthreads();

        // ---- T: rows 4w..4w+3 ----
        #pragma unroll 1
        for (int rr2 = 0; rr2 < 4; ++rr2) {
            const int r = (w << 2) + rr2;
            const unsigned short* srow = s_sims + r * SST2_;
            ushort8v rv[2];
            rv[0] = *(const ushort8v*)(srow + (lane << 3));
            rv[1] = *(const ushort8v*)(srow + 512 + (lane << 3));
            float bv = -3e38f;
            #pragma unroll
            for (int j = 0; j < 2; ++j)
                #pragma unroll
                for (int e = 0; e < 8; ++e) bv = fmaxf(bv, bf2f(rv[j][e]));
            bvmax[rr2] = fmaxf(bvmax[rr2], bv);
            u32* cr = cand + (size_t)(rg0 + r) * 96;
            if (hf == 0) {
                // provisional half-0 threshold (16-bit radix on lane maxima)
                u32 key = flip16(f2bf(bv));
                u32 thr = 0;
                #pragma unroll
                for (int bp = 15; bp >= 0; --bp) {
                    u32 tt = thr | (1u << bp);
                    if (__popcll(__ballot(key >= tt)) >= 32) thr = tt;
                }
                float thrv = bf2f(unflip16(thr)) - 0.01f;
                int base = 0;
                #pragma unroll
                for (int j = 0; j < 2; ++j) {
                    #pragma unroll
                    for (int e = 0; e < 8; ++e) {
                        bool pred = bf2f(rv[j][e]) >= thrv;
                        u64 mk = __ballot(pred);
                        if (pred) {
                            int pos = base + __popcll(mk & ((1ull << lane) - 1));
                            if (pos < 96)
                                cr[pos] = ((u32)rv[j][e] << 16)
                                        | (u32)((j << 9) + (lane << 3) + e);
                        }
                        base += __popcll(mk);
                    }
                }
                c0[rr2] = base < 96 ? base : 96;
            } else {
                // full-row threshold from running lane maxima
                u32 key = flip16(f2bf(bvmax[rr2]));
                u32 thr = 0;
                #pragma unroll
                for (int bp = 15; bp >= 0; --bp) {
                    u32 tt = thr | (1u << bp);
                    if (__popcll(__ballot(key >= tt)) >= 32) thr = tt;
                }
                float thrv = bf2f(unflip16(thr)) - 0.01f;
                const int cc0 = c0[rr2];
                u32 e0 = (lane < cc0) ? cr[lane] : 0u;
                u32 e1 = (64 + lane < cc0) ? cr[64 + lane] : 0u;
                int base = 0;
                {   // filter provisional h0 list with the tighter threshold
                    bool pred = (lane < cc0)
                              && (bf2f((unsigned short)(e0 >> 16)) >= thrv);
                    u64 mk = __ballot(pred);
                    if (pred) {
                        int pos = __popcll(mk & ((1ull << lane) - 1));
                        cr[pos] = e0;   // pos < cc0 <= 96
                    }
                    base = __popcll(mk);
                }
                if (cc0 > 64) {
                    bool pred = (64 + lane < cc0)
                              && (bf2f((unsigned short)(e1 >> 16)) >= thrv);
                    u64 mk = __ballot(pred);
                    if (pred) {
                        int pos = base + __popcll(mk & ((1ull << lane) - 1));
                        if (pos < 96) cr[pos] = e1;
                    }
                    base += __popcll(mk);
                }
                // append half-1 candidates (ascending m preserves stable order)
                #pragma unroll
                for (int j = 0; j < 2; ++j) {
                    #pragma unroll
                    for (int e = 0; e < 8; ++e) {
                        bool pred = bf2f(rv[j][e]) >= thrv;
                        u64 mk = __ballot(pred);
                        if (pred) {
                            int pos = base + __popcll(mk & ((1ull << lane) - 1));
                            if (pos < 96)
                                cr[pos] = ((u32)rv[j][e] << 16)
                                        | (u32)(1024 + (j << 9) + (lane << 3) + e);
                        }
                        base += __popcll(mk);
                    }
                }
                if (lane == 0) candC[rg0 + r] = base < 96 ? base : 96;
            }
        }

        // ---- L1: p@v for this half (wave w: its 256-k slab), acc in regs ----
        #pragma unroll
        for (int g = 0; g < 4; ++g) {
            bf16x8 bvv[2][4];
            #pragma unroll
            for (int t2 = 0; t2 < 2; ++t2)
                #pragma unroll
                for (int nn = 0; nn < 4; ++nn)
                    bvv[t2][nn] = *(const bf16x8*)(vtb + (size_t)((nn << 4) + n15) * L_
                                  + (hf << 10) + (w << 8) + (g << 6) + (t2 << 5) + (quad << 3));
            #pragma unroll
            for (int t2 = 0; t2 < 2; ++t2) {
                int mb = (w << 8) + (g << 6) + (t2 << 5);
                ushort8v pu = *(const ushort8v*)(s_sims + n15 * SST2_ + mb + (quad << 3));
                bf16x8 af;
                #pragma unroll
                for (int e = 0; e < 8; ++e) {
                    float p = __expf(SCALE_ * bf2f(pu[e]));
                    psum += p;
                    af[e] = (__bf16)p;
                }
                #pragma unroll
                for (int nn = 0; nn < 4; ++nn)
                    accL[nn] = __builtin_amdgcn_mfma_f32_16x16x32_bf16(af, bvv[t2][nn], accL[nn], 0, 0, 0);
            }
        }
        __syncthreads();   // sims consumed; next half may overwrite
    }

    // ---- reduce across the 4 waves ----
    psum += __shfl_xor(psum, 16);
    psum += __shfl_xor(psum, 32);
    if (lane < 16) atomicAdd(&s_denom[lane], psum);
    #pragma unroll
    for (int nn = 0; nn < 4; ++nn)
        #pragma unroll
        for (int rr = 0; rr < 4; ++rr)
            atomicAdd(&s_local[(quad << 2) + rr][(nn << 4) + n15], accL[nn][rr]);
    __syncthreads();

    // ---- write local part into attn ----
    {
        int r  = t >> 4;
        int d0 = (t & 15) << 2;
        float inv = 1.f / s_denom[r];
        float* op = attn + ((size_t)(b * L_ + l0 + r)) * DM_ + h * DH_ + d0;
        op[0] = s_local[r][d0+0] * inv;
        op[1] = s_local[r][d0+1] * inv;
        op[2] = s_local[r][d0+2] * inv;
        op[3] = s_local[r][d0+3] * inv;
    }
}

// ---------------------------------------------------------------------------
// topk_merge (R8): cooperative coalesced refine (16 lanes per candidate,
// contiguous 256B row reads), dots to LDS, then radix top-32 + retrieved.
// ---------------------------------------------------------------------------
__global__ __launch_bounds__(256)
void topk_merge(const float* __restrict__ q, const float* __restrict__ kn,
                const u32* __restrict__ cand, const int* __restrict__ candC,
                float* __restrict__ attn) {
    const int wv   = threadIdx.x >> 6;
    const int lane = threadIdx.x & 63;
    const int row  = (blockIdx.x << 2) + wv;
    const int l = row & (L_ - 1);
    const int h = (row >> 11) & (NH_ - 1);
    const int b = row >> 15;
    __shared__ float s_dot[4][96];
    __shared__ __align__(16) u64 s_sel[4][32];

    const int C = candC[row];
    const u32* cr = cand + (size_t)row * 96;
    const float* knb = kn + (size_t)b * L_ * DH_;
    const float* qr  = q + ((size_t)(b * L_ + l)) * DM_ + h * DH_;

    // preload candidate indices into registers (2 per lane covers C<=96 via shfl)
    int mreg0 = (lane < C) ? (int)(cr[lane] & 0xffffu) : 0;
    int mreg1 = (64 + lane < C) ? (int)(cr[64 + lane] & 0xffffu) : 0;

    const int cg = lane >> 4;    // candidate within pass
    const int dg = lane & 15;    // dim group (float4)
    float4 qx = *(const float4*)(qr + (dg << 2));   // fixed per lane

    #pragma unroll 2
    for (int base = 0; base < C; base += 4) {
        int ci = base + cg;
        int src = ci & 63;
        int mA = __shfl(mreg0, src);
        int mB = __shfl(mreg1, src);
        int m  = (ci < 64) ? mA : mB;
        float4 kx = *(const float4*)(knb + (size_t)m * DH_ + (dg << 2));  // coalesced 256B/group
        float p = kx.x * qx.x + kx.y * qx.y + kx.z * qx.z + kx.w * qx.w;
        p += __shfl_xor(p, 1);
        p += __shfl_xor(p, 2);
        p += __shfl_xor(p, 4);
        p += __shfl_xor(p, 8);
        if (dg == 0 && ci < C) s_dot[wv][ci] = p;
    }

    // per-lane keys from refined dots (same wave -> lgkm ordering suffices)
    float dotA = (lane < C) ? s_dot[wv][lane] : 0.f;
    float dotB = (64 + lane < C) ? s_dot[wv][64 + lane] : 0.f;
    u32 keyA = (lane < C) ? flipf(dotA) : 0u;
    u32 keyB = (64 + lane < C) ? flipf(dotB) : 0u;

    u32 thr2 = 0;
    if (C <= 64) {
        #pragma unroll
        for (int bp = 31; bp >= 0; --bp) {
            u32 tt = thr2 | (1u << bp);
            if (__popcll(__ballot(keyA >= tt)) >= 32) thr2 = tt;
        }
    } else {
        #pragma unroll
        for (int bp = 31; bp >= 0; --bp) {
            u32 tt = thr2 | (1u << bp);
            int c2 = __popcll(__ballot(keyA >= tt)) + __popcll(__ballot(keyB >= tt));
            if (c2 >= 32) thr2 = tt;
        }
    }
    {
        bool pA = keyA >= thr2;
        u64 mkA = __ballot(pA);
        if (pA) {
            int pos = __popcll(mkA & ((1ull << lane) - 1));
            if (pos < 32) {
                float pt = __expf(SCALE_ * dotA);
                s_sel[wv][pos] = ((u64)__float_as_uint(pt) << 32) | (u32)mreg0;
            }
        }
        if (C > 64) {
            int cA = __popcll(mkA);
            bool pB = keyB >= thr2;
            u64 mkB = __ballot(pB);
            if (pB) {
                int pos = cA + __popcll(mkB & ((1ull << lane) - 1));
                if (pos < 32) {
                    float pt = __expf(SCALE_ * dotB);
                    s_sel[wv][pos] = ((u64)__float_as_uint(pt) << 32) | (u32)mreg1;
                }
            }
        }
    }
    // retrieved (wave-local LDS ordering; coalesced k gathers)
    {
        float pts[32];
        int   ms[32];
        #pragma unroll
        for (int i = 0; i < 32; ++i) {
            u64 s0 = s_sel[wv][i];
            pts[i] = __uint_as_float((u32)(s0 >> 32));
            ms[i]  = (int)(u32)(s0 & 0xffffffffu);
        }
        const float* knb2 = knb + lane;
        float kvv[32];
        #pragma unroll
        for (int i = 0; i < 32; ++i) kvv[i] = knb2[(size_t)ms[i] * DH_];
        float rs = 0.f, ret = 0.f;
        #pragma unroll
        for (int i = 0; i < 16; ++i) {
            rs  += pts[2*i] + pts[2*i+1];
            ret += pts[2*i] * kvv[2*i] + pts[2*i+1] * kvv[2*i+1];
        }
        size_t oa = ((size_t)(b * L_ + l)) * DM_ + h * DH_ + lane;
        attn[oa] = attn[oa] + ret / rs;
    }
}

// ---------------------------------------------------------------------------
extern "C" void kernel_launch(void* const* d_in, const int* in_sizes, int n_in,
                              void* d_out, int out_size, void* d_ws, size_t ws_size,
                              hipStream_t stream) {
    const float* q_in     = (const float*)d_in[0];
    const float* kv_in    = (const float*)d_in[1];
    const float* w_q      = (const float*)d_in[2];
    const float* w_kv     = (const float*)d_in[3];
    const float* w_concat = (const float*)d_in[4];
    float* out = (float*)d_out;

    float* ws   = (float*)d_ws;
    float* q    = ws;                    // 4,194,304 f
    float* attn = ws + 4194304;          // 4,194,304 f
    float* kv   = attn;                  // aliased: kv dead before attn written
    float* kn   = ws + 8388608;          // 262,144 f
    float* invn = ws + 8650752;          // 256 f
    unsigned short* us = (unsigned short*)(ws + 8651008);
    unsigned short* kh_u = us;                   // 262,144
    unsigned short* vT_u = us + 262144;          // 262,144
    unsigned short* wq1  = us + 524288;          // 1,048,576 x3
    unsigned short* wq2  = wq1 + 1048576;
    unsigned short* wq3  = wq2 + 1048576;
    unsigned short* wc1  = wq3 + 1048576;        // 1,048,576 x2
    unsigned short* wc2  = wc1 + 1048576;
    unsigned short* wkv1 = wc2 + 1048576;        // 131,072 x3
    unsigned short* wkv2 = wkv1 + 131072;
    unsigned short* wkv3 = wkv2 + 131072;
    u32* cand = (u32*)(wkv3 + 131072);           // 65536*96 u32 = 25.2 MB
    unsigned short* wc3 = (unsigned short*)cand; // alias: dead before cand written
    int* candC = (int*)(cand + 65536 * 96);      // 65,536 ints
    __bf16* kh = (__bf16*)kh_u;
    __bf16* vT = (__bf16*)vT_u;

    // weight prep
    wsplit3<<<dim3(DM_ / 64, DM_ / 64), 256, 0, stream>>>(w_q, wq1, wq2, wq3, DM_, DM_);
    wsplit3<<<dim3(DM_ / 64, DM_ / 64), 256, 0, stream>>>(w_concat, wc1, wc2, wc3, DM_, DM_);
    wsplit3<<<dim3(128 / 64, DM_ / 64), 256, 0, stream>>>(w_kv, wkv1, wkv2, wkv3, DM_, 128);

    // projections
    gemm6p<<<dim3(DM_ / 64, (B_ * L_) / 128), 256, 0, stream>>>(q_in, wq1, wq2, wq3, q, DM_, DM_);
    gemm6p<<<dim3(128 / 64, (B_ * L_) / 128), 256, 0, stream>>>(kv_in, wkv1, wkv2, wkv3, kv, 128, DM_);

    col_norms<<<B_ * 128, 256, 0, stream>>>(kv, invn);
    scale_kv<<<dim3(L_ / 64, B_), 256, 0, stream>>>(kv, invn, kn, kh, vT);

    // attention
    attn_part<<<dim3(L_ / 16, NH_, B_), 256, 0, stream>>>(q, kh, vT, attn, cand, candC);
    topk_merge<<<(B_ * NH_ * L_) / 4, 256, 0, stream>>>(q, kn, cand, candC, attn);

    // output projection (3-product)
    gemm3p<<<dim3(DM_ / 64, (B_ * L_) / 128), 256, 0, stream>>>(attn, wc1, wc2, out, DM_, DM_);
}